// Round 2
// baseline (11725.500 us; speedup 1.0000x reference)
//
#include <hip/hip_runtime.h>
#include <hip/hip_bf16.h>

#define BATCH 8
#define NH 12
#define DIM 768
#define HD 64
#define NQ 1568       // 8*14*14
#define TT 8
#define HH_ 14
#define WW_ 14
#define LK 392        // 8*7*7
#define SCALE 0.125f
#define EPS 1e-5f

// ---------------- GEMM: 64x64 tile, 256 threads, 4x4 micro-tile ----------------
// EPI==0: out[row*Ncol+col] = acc + bias[col]
// EPI==1: qkv scatter: col = s*768 + h*64 + c -> qkv[((s*B+b)*NH+h)*N + n][c]
template<int EPI>
__global__ __launch_bounds__(256) void gemm64(const float* __restrict__ A,
                                              const float* __restrict__ Bw,
                                              const float* __restrict__ bias,
                                              float* __restrict__ out,
                                              int M, int Ncol, int K) {
  __shared__ float As[16][68];  // transposed A tile: As[k][m]
  __shared__ float Bs[16][68];  // Bs[k][n]
  const int col0 = blockIdx.x * 64;
  const int row0 = blockIdx.y * 64;
  const int tid = threadIdx.x;
  const int tx = tid & 15, ty = tid >> 4;
  float acc[4][4] = {};

  const int am = tid >> 2, ak = (tid & 3) * 4;   // A load: row am, k-offset ak (float4)
  const int bk = tid >> 4, bn = (tid & 15) * 4;  // B load: k bk, col bn (float4)

  for (int k0 = 0; k0 < K; k0 += 16) {
    float4 av = *(const float4*)(A + (size_t)(row0 + am) * K + k0 + ak);
    float4 bv = *(const float4*)(Bw + (size_t)(k0 + bk) * Ncol + col0 + bn);
    __syncthreads();
    As[ak + 0][am] = av.x; As[ak + 1][am] = av.y;
    As[ak + 2][am] = av.z; As[ak + 3][am] = av.w;
    *(float4*)&Bs[bk][bn] = bv;
    __syncthreads();
#pragma unroll
    for (int kk = 0; kk < 16; ++kk) {
      float4 a4 = *(float4*)&As[kk][ty * 4];
      float4 b4 = *(float4*)&Bs[kk][tx * 4];
      float aa[4] = {a4.x, a4.y, a4.z, a4.w};
      float bb[4] = {b4.x, b4.y, b4.z, b4.w};
#pragma unroll
      for (int i = 0; i < 4; ++i)
#pragma unroll
        for (int j = 0; j < 4; ++j) acc[i][j] += aa[i] * bb[j];
    }
  }

  const int colb = col0 + tx * 4;
#pragma unroll
  for (int i = 0; i < 4; ++i) {
    int row = row0 + ty * 4 + i;
    float4 r;
    r.x = acc[i][0] + bias[colb + 0];
    r.y = acc[i][1] + bias[colb + 1];
    r.z = acc[i][2] + bias[colb + 2];
    r.w = acc[i][3] + bias[colb + 3];
    if (EPI == 0) {
      *(float4*)(out + (size_t)row * Ncol + colb) = r;
    } else {
      int b = row / NQ, n = row % NQ;
      int s = colb / DIM, rr = colb % DIM;
      int h = rr >> 6, cc = rr & 63;
      *(float4*)(out + ((((size_t)s * BATCH + b) * NH + h) * NQ + n) * HD + cc) = r;
    }
  }
}

// ---------------- depthwise 3x3x3 pool + LayerNorm(64) ----------------
// one wave per output position, lane = channel
__global__ __launch_bounds__(256) void pool_ln(const float* __restrict__ in,
                                               float* __restrict__ out,
                                               const float* __restrict__ wgt,
                                               const float* __restrict__ g,
                                               const float* __restrict__ bb,
                                               int OT, int OH, int OW,
                                               int sh, int sw) {
  const int OL = OT * OH * OW;
  const int wid = (blockIdx.x * blockDim.x + threadIdx.x) >> 6;
  const int lane = threadIdx.x & 63;
  const int total = BATCH * NH * OL;
  if (wid >= total) return;
  const int bh = wid / OL, opos = wid % OL;
  const int ot = opos / (OH * OW);
  const int r = opos % (OH * OW);
  const int oy = r / OW, ox = r % OW;
  const float* base = in + (size_t)bh * NQ * HD;
  const int c = lane;
  float acc = 0.f;
#pragma unroll
  for (int dt = 0; dt < 3; ++dt) {
    int it = ot + dt - 1;
    if (it < 0 || it >= TT) continue;
#pragma unroll
    for (int dy = 0; dy < 3; ++dy) {
      int iy = oy * sh + dy - 1;
      if (iy < 0 || iy >= HH_) continue;
#pragma unroll
      for (int dx = 0; dx < 3; ++dx) {
        int ix = ox * sw + dx - 1;
        if (ix < 0 || ix >= WW_) continue;
        int n = (it * HH_ + iy) * WW_ + ix;
        acc += base[(size_t)n * HD + c] * wgt[c * 27 + (dt * 3 + dy) * 3 + dx];
      }
    }
  }
  // LayerNorm across 64 lanes
  float s = acc;
#pragma unroll
  for (int off = 32; off; off >>= 1) s += __shfl_xor(s, off, 64);
  float mean = s * (1.f / 64.f);
  float d = acc - mean;
  float vs = d * d;
#pragma unroll
  for (int off = 32; off; off >>= 1) vs += __shfl_xor(vs, off, 64);
  float inv = rsqrtf(vs * (1.f / 64.f) + EPS);
  out[(size_t)wid * HD + c] = d * inv * g[c] + bb[c];
}

// ---------------- rel-pos bias precompute: rel[q][j], j: 0-6 h, 7-13 w, 14-21 t ---
__global__ __launch_bounds__(256) void rel_kernel(const float* __restrict__ qp,
                                                  const float* __restrict__ Rh,
                                                  const float* __restrict__ Rw,
                                                  const float* __restrict__ Rt,
                                                  float* __restrict__ rel) {
  const int idx = blockIdx.x * blockDim.x + threadIdx.x;
  const int total = BATCH * NH * NQ * 22;
  if (idx >= total) return;
  const int j = idx % 22;
  const int q = idx / 22;
  const int n = q % NQ;
  const int t = n / (HH_ * WW_);
  const int r = n % (HH_ * WW_);
  const int y = r / WW_, x = r % WW_;
  const float* R;
  if (j < 7)       R = Rh + (size_t)(y - 2 * j + 12) * HD;
  else if (j < 14) R = Rw + (size_t)(x - 2 * (j - 7) + 12) * HD;
  else             R = Rt + (size_t)(t - (j - 14) + 7) * HD;
  const float* qrow = qp + (size_t)q * HD;
  float acc = 0.f;
#pragma unroll
  for (int c = 0; c < HD; c += 4) {
    float4 a = *(const float4*)(qrow + c);
    float4 b = *(const float4*)(R + c);
    acc += a.x * b.x + a.y * b.y + a.z * b.z + a.w * b.w;
  }
  rel[(size_t)q * 24 + j] = acc;
}

// ---------------- fused attention: 16 queries per block, full 392 logits in LDS ----
#define QT 16
__global__ __launch_bounds__(256) void attn_kernel(const float* __restrict__ qp,
                                                   const float* __restrict__ kp,
                                                   const float* __restrict__ vp,
                                                   const float* __restrict__ rel,
                                                   float* __restrict__ out) {
  __shared__ float sQ[QT][68];
  __shared__ float sK[64][68];
  __shared__ float sS[QT][404];
  __shared__ float sRel[QT][24];
  __shared__ float sSum[QT];
  const int qb = blockIdx.x;   // 0..97
  const int h = blockIdx.y;    // 0..11
  const int b = blockIdx.z;    // 0..7
  const int tid = threadIdx.x;
  const int bh = b * NH + h;
  const int q0 = qb * QT;

  // load Q tile (QT*64 = 1024 floats, one float4 per thread)
  {
    const float* qbase = qp + ((size_t)bh * NQ + q0) * HD;
    int e = tid * 4;
    int row = e >> 6, c = e & 63;
    *(float4*)&sQ[row][c] = *(const float4*)(qbase + row * HD + c);
  }
  // load rel values (QT*22 = 352 entries, grid-stride over 256 threads)
  for (int e = tid; e < QT * 22; e += 256) {
    int row = e / 22, j = e % 22;
    sRel[row][j] = rel[((size_t)bh * NQ + q0 + row) * 24 + j];
  }

  const float* kbase = kp + (size_t)bh * LK * HD;
  const int qt = tid >> 4;      // 0..15
  const int klane = tid & 15;   // 0..15

  // ---- QK^T + bias ----
  for (int t0 = 0; t0 < LK; t0 += 64) {
    int tsz = min(64, LK - t0);
    __syncthreads();
    for (int e = tid * 4; e < tsz * 64; e += 1024) {
      int row = e >> 6, c = e & 63;
      *(float4*)&sK[row][c] = *(const float4*)(kbase + (size_t)(t0 + row) * HD + c);
    }
    __syncthreads();
    float acc[4] = {0.f, 0.f, 0.f, 0.f};
#pragma unroll
    for (int c = 0; c < HD; c += 4) {
      float4 qv = *(float4*)&sQ[qt][c];
#pragma unroll
      for (int ii = 0; ii < 4; ++ii) {
        int kk = klane + ii * 16;
        float4 kv = *(float4*)&sK[kk][c];
        acc[ii] += qv.x * kv.x + qv.y * kv.y + qv.z * kv.z + qv.w * kv.w;
      }
    }
#pragma unroll
    for (int ii = 0; ii < 4; ++ii) {
      int kk = klane + ii * 16;
      if (kk < tsz) {
        int kg = t0 + kk;
        int kt = kg / 49, kr = kg % 49, ky = kr / 7, kx = kr % 7;
        sS[qt][kg] = acc[ii] * SCALE + sRel[qt][ky] + sRel[qt][7 + kx] + sRel[qt][14 + kt];
      }
    }
  }
  __syncthreads();

  // ---- softmax over 392 (4 waves x 4 rows) ----
  {
    int wave = tid >> 6, lane = tid & 63;
    for (int row = wave * 4; row < wave * 4 + 4; ++row) {
      float m = -1e30f;
      for (int k = lane; k < LK; k += 64) m = fmaxf(m, sS[row][k]);
#pragma unroll
      for (int off = 32; off; off >>= 1) m = fmaxf(m, __shfl_xor(m, off, 64));
      float sum = 0.f;
      for (int k = lane; k < LK; k += 64) {
        float e = __expf(sS[row][k] - m);
        sS[row][k] = e;
        sum += e;
      }
#pragma unroll
      for (int off = 32; off; off >>= 1) sum += __shfl_xor(sum, off, 64);
      if (lane == 0) sSum[row] = sum;
    }
  }

  // ---- AV ----
  const float* vbase = vp + (size_t)bh * LK * HD;
  const int c0 = (tid & 15) * 4;
  float o[4] = {0.f, 0.f, 0.f, 0.f};
  for (int t0 = 0; t0 < LK; t0 += 64) {
    int tsz = min(64, LK - t0);
    __syncthreads();
    for (int e = tid * 4; e < tsz * 64; e += 1024) {
      int row = e >> 6, c = e & 63;
      *(float4*)&sK[row][c] = *(const float4*)(vbase + (size_t)(t0 + row) * HD + c);
    }
    __syncthreads();
    for (int kk = 0; kk < tsz; ++kk) {
      float p = sS[qt][t0 + kk];
      float4 vv = *(float4*)&sK[kk][c0];
      o[0] += p * vv.x; o[1] += p * vv.y; o[2] += p * vv.z; o[3] += p * vv.w;
    }
  }
  float inv = 1.f / sSum[qt];
  int qg = q0 + qt;
  float4 res = make_float4(o[0] * inv, o[1] * inv, o[2] * inv, o[3] * inv);
  *(float4*)(out + ((size_t)b * NQ + qg) * DIM + h * HD + c0) = res;
}

// ---------------- launch ----------------
extern "C" void kernel_launch(void* const* d_in, const int* in_sizes, int n_in,
                              void* d_out, int out_size, void* d_ws, size_t ws_size,
                              hipStream_t stream) {
  const float* x        = (const float*)d_in[0];
  const float* w_qkv    = (const float*)d_in[1];
  const float* b_qkv    = (const float*)d_in[2];
  const float* pool_q_w = (const float*)d_in[3];
  const float* pool_k_w = (const float*)d_in[4];
  const float* pool_v_w = (const float*)d_in[5];
  const float* norm_q_g = (const float*)d_in[6];
  const float* norm_q_b = (const float*)d_in[7];
  const float* norm_k_g = (const float*)d_in[8];
  const float* norm_k_b = (const float*)d_in[9];
  const float* norm_v_g = (const float*)d_in[10];
  const float* norm_v_b = (const float*)d_in[11];
  const float* rel_h    = (const float*)d_in[12];
  const float* rel_w    = (const float*)d_in[13];
  const float* rel_t    = (const float*)d_in[14];
  const float* w_proj   = (const float*)d_in[15];
  const float* b_proj   = (const float*)d_in[16];
  float* out = (float*)d_out;

  float* ws = (float*)d_ws;
  const size_t NQKV_THIRD = (size_t)BATCH * NH * NQ * HD;     // 9,633,792
  float* qkv  = ws;                                            // 3*NQKV_THIRD
  float* qpb  = ws + 3 * NQKV_THIRD;
  float* kpb  = qpb + NQKV_THIRD;
  float* vpb  = kpb + (size_t)BATCH * NH * LK * HD;
  float* relb = vpb + (size_t)BATCH * NH * LK * HD;
  float* attn_out = ws;  // reuse qkv region (free after pooling)

  const int M = BATCH * NQ;  // 12544

  // 1. QKV projection -> scattered [s][b][h][n][c]
  gemm64<1><<<dim3(3 * DIM / 64, M / 64), 256, 0, stream>>>(
      x, w_qkv, b_qkv, qkv, M, 3 * DIM, DIM);

  // 2. pool + LN
  {
    int wq = BATCH * NH * NQ;   // q output positions
    pool_ln<<<(wq + 3) / 4, 256, 0, stream>>>(qkv, qpb, pool_q_w, norm_q_g, norm_q_b,
                                              8, 14, 14, 1, 1);
    int wk = BATCH * NH * LK;
    pool_ln<<<(wk + 3) / 4, 256, 0, stream>>>(qkv + NQKV_THIRD, kpb, pool_k_w,
                                              norm_k_g, norm_k_b, 8, 7, 7, 2, 2);
    pool_ln<<<(wk + 3) / 4, 256, 0, stream>>>(qkv + 2 * NQKV_THIRD, vpb, pool_v_w,
                                              norm_v_g, norm_v_b, 8, 7, 7, 2, 2);
  }

  // 3. rel-pos dot products
  {
    int total = BATCH * NH * NQ * 22;
    rel_kernel<<<(total + 255) / 256, 256, 0, stream>>>(qpb, rel_h, rel_w, rel_t, relb);
  }

  // 4. fused attention
  attn_kernel<<<dim3(NQ / QT, NH, BATCH), 256, 0, stream>>>(qpb, kpb, vpb, relb, attn_out);

  // 5. output projection
  gemm64<0><<<dim3(DIM / 64, M / 64), 256, 0, stream>>>(
      attn_out, w_proj, b_proj, out, M, DIM, DIM);
}

// Round 3
// 1915.560 us; speedup vs baseline: 6.1212x; 6.1212x over previous
//
#include <hip/hip_runtime.h>
#include <hip/hip_bf16.h>

#define BATCH 8
#define NH 12
#define DIM 768
#define HD 64
#define NQ 1568       // 8*14*14
#define TT 8
#define HH_ 14
#define WW_ 14
#define LK 392        // 8*7*7
#define SCALE 0.125f
#define EPS 1e-5f

// ---------------- GEMM: 64x64 tile, 256 threads, 4x4 micro-tile ----------------
template<int EPI>
__global__ __launch_bounds__(256) void gemm64(const float* __restrict__ A,
                                              const float* __restrict__ Bw,
                                              const float* __restrict__ bias,
                                              float* __restrict__ out,
                                              int M, int Ncol, int K) {
  __shared__ float As[16][68];  // transposed A tile: As[k][m]
  __shared__ float Bs[16][68];  // Bs[k][n]
  const int col0 = blockIdx.x * 64;
  const int row0 = blockIdx.y * 64;
  const int tid = threadIdx.x;
  const int tx = tid & 15, ty = tid >> 4;
  float acc[4][4] = {};

  const int am = tid >> 2, ak = (tid & 3) * 4;
  const int bk = tid >> 4, bn = (tid & 15) * 4;

  for (int k0 = 0; k0 < K; k0 += 16) {
    float4 av = *(const float4*)(A + (size_t)(row0 + am) * K + k0 + ak);
    float4 bv = *(const float4*)(Bw + (size_t)(k0 + bk) * Ncol + col0 + bn);
    __syncthreads();
    As[ak + 0][am] = av.x; As[ak + 1][am] = av.y;
    As[ak + 2][am] = av.z; As[ak + 3][am] = av.w;
    *(float4*)&Bs[bk][bn] = bv;
    __syncthreads();
#pragma unroll 4
    for (int kk = 0; kk < 16; ++kk) {
      float4 a4 = *(float4*)&As[kk][ty * 4];
      float4 b4 = *(float4*)&Bs[kk][tx * 4];
      float aa[4] = {a4.x, a4.y, a4.z, a4.w};
      float bb[4] = {b4.x, b4.y, b4.z, b4.w};
#pragma unroll
      for (int i = 0; i < 4; ++i)
#pragma unroll
        for (int j = 0; j < 4; ++j) acc[i][j] += aa[i] * bb[j];
    }
  }

  const int colb = col0 + tx * 4;
#pragma unroll
  for (int i = 0; i < 4; ++i) {
    int row = row0 + ty * 4 + i;
    float4 r;
    r.x = acc[i][0] + bias[colb + 0];
    r.y = acc[i][1] + bias[colb + 1];
    r.z = acc[i][2] + bias[colb + 2];
    r.w = acc[i][3] + bias[colb + 3];
    if (EPI == 0) {
      *(float4*)(out + (size_t)row * Ncol + colb) = r;
    } else {
      int b = row / NQ, n = row % NQ;
      int s = colb / DIM, rr = colb % DIM;
      int h = rr >> 6, cc = rr & 63;
      *(float4*)(out + ((((size_t)s * BATCH + b) * NH + h) * NQ + n) * HD + cc) = r;
    }
  }
}

// ---------------- depthwise 3x3x3 pool + LayerNorm(64) ----------------
__global__ __launch_bounds__(256) void pool_ln(const float* __restrict__ in,
                                               float* __restrict__ out,
                                               const float* __restrict__ wgt,
                                               const float* __restrict__ g,
                                               const float* __restrict__ bb,
                                               int OT, int OH, int OW,
                                               int sh, int sw) {
  const int OL = OT * OH * OW;
  const int wid = (blockIdx.x * blockDim.x + threadIdx.x) >> 6;
  const int lane = threadIdx.x & 63;
  const int total = BATCH * NH * OL;
  if (wid >= total) return;
  const int bh = wid / OL, opos = wid % OL;
  const int ot = opos / (OH * OW);
  const int r = opos % (OH * OW);
  const int oy = r / OW, ox = r % OW;
  const float* base = in + (size_t)bh * NQ * HD;
  const int c = lane;
  float acc = 0.f;
#pragma unroll
  for (int dt = 0; dt < 3; ++dt) {
    int it = ot + dt - 1;
    if (it < 0 || it >= TT) continue;
#pragma unroll
    for (int dy = 0; dy < 3; ++dy) {
      int iy = oy * sh + dy - 1;
      if (iy < 0 || iy >= HH_) continue;
#pragma unroll
      for (int dx = 0; dx < 3; ++dx) {
        int ix = ox * sw + dx - 1;
        if (ix < 0 || ix >= WW_) continue;
        int n = (it * HH_ + iy) * WW_ + ix;
        acc += base[(size_t)n * HD + c] * wgt[c * 27 + (dt * 3 + dy) * 3 + dx];
      }
    }
  }
  float s = acc;
#pragma unroll
  for (int off = 32; off; off >>= 1) s += __shfl_xor(s, off, 64);
  float mean = s * (1.f / 64.f);
  float d = acc - mean;
  float vs = d * d;
#pragma unroll
  for (int off = 32; off; off >>= 1) vs += __shfl_xor(vs, off, 64);
  float inv = rsqrtf(vs * (1.f / 64.f) + EPS);
  out[(size_t)wid * HD + c] = d * inv * g[c] + bb[c];
}

// ---------------- rel-pos bias precompute ----------------
__global__ __launch_bounds__(256) void rel_kernel(const float* __restrict__ qp,
                                                  const float* __restrict__ Rh,
                                                  const float* __restrict__ Rw,
                                                  const float* __restrict__ Rt,
                                                  float* __restrict__ rel) {
  const int idx = blockIdx.x * blockDim.x + threadIdx.x;
  const int total = BATCH * NH * NQ * 22;
  if (idx >= total) return;
  const int j = idx % 22;
  const int q = idx / 22;
  const int n = q % NQ;
  const int t = n / (HH_ * WW_);
  const int r = n % (HH_ * WW_);
  const int y = r / WW_, x = r % WW_;
  const float* R;
  if (j < 7)       R = Rh + (size_t)(y - 2 * j + 12) * HD;
  else if (j < 14) R = Rw + (size_t)(x - 2 * (j - 7) + 12) * HD;
  else             R = Rt + (size_t)(t - (j - 14) + 7) * HD;
  const float* qrow = qp + (size_t)q * HD;
  float acc = 0.f;
#pragma unroll 4
  for (int c = 0; c < HD; c += 4) {
    float4 a = *(const float4*)(qrow + c);
    float4 b = *(const float4*)(R + c);
    acc += a.x * b.x + a.y * b.y + a.z * b.z + a.w * b.w;
  }
  rel[(size_t)q * 24 + j] = acc;
}

// ---------------- fused attention: 16 queries per block ----------------
#define QT 16
__global__ __launch_bounds__(256) void attn_kernel(const float* __restrict__ qp,
                                                   const float* __restrict__ kp,
                                                   const float* __restrict__ vp,
                                                   const float* __restrict__ rel,
                                                   float* __restrict__ out) {
  __shared__ float sQ[QT][68];
  __shared__ float sK[64][68];
  __shared__ float sS[QT][404];
  __shared__ float sRel[QT][24];
  __shared__ float sSum[QT];
  const int qb = blockIdx.x;
  const int h = blockIdx.y;
  const int b = blockIdx.z;
  const int tid = threadIdx.x;
  const int bh = b * NH + h;
  const int q0 = qb * QT;

  {
    const float* qbase = qp + ((size_t)bh * NQ + q0) * HD;
    int e = tid * 4;
    int row = e >> 6, c = e & 63;
    *(float4*)&sQ[row][c] = *(const float4*)(qbase + row * HD + c);
  }
  for (int e = tid; e < QT * 22; e += 256) {
    int row = e / 22, j = e % 22;
    sRel[row][j] = rel[((size_t)bh * NQ + q0 + row) * 24 + j];
  }

  const float* kbase = kp + (size_t)bh * LK * HD;
  const int qt = tid >> 4;
  const int klane = tid & 15;

  // ---- QK^T + bias ----
  for (int t0 = 0; t0 < LK; t0 += 64) {
    int tsz = min(64, LK - t0);
    __syncthreads();
    for (int e = tid * 4; e < tsz * 64; e += 1024) {
      int row = e >> 6, c = e & 63;
      *(float4*)&sK[row][c] = *(const float4*)(kbase + (size_t)(t0 + row) * HD + c);
    }
    __syncthreads();
    float acc[4] = {0.f, 0.f, 0.f, 0.f};
    // NOTE: bounded unroll — full unroll (80 hoisted ds_read_b128) spilled to
    // scratch (13.5 GB of scratch writes, VGPR=256) in R1.
#pragma unroll 4
    for (int c = 0; c < HD; c += 4) {
      float4 qv = *(float4*)&sQ[qt][c];
#pragma unroll
      for (int ii = 0; ii < 4; ++ii) {
        int kk = klane + ii * 16;
        float4 kv = *(float4*)&sK[kk][c];
        acc[ii] += qv.x * kv.x + qv.y * kv.y + qv.z * kv.z + qv.w * kv.w;
      }
    }
#pragma unroll
    for (int ii = 0; ii < 4; ++ii) {
      int kk = klane + ii * 16;
      if (kk < tsz) {
        int kg = t0 + kk;
        int kt = kg / 49, kr = kg % 49, ky = kr / 7, kx = kr % 7;
        sS[qt][kg] = acc[ii] * SCALE + sRel[qt][ky] + sRel[qt][7 + kx] + sRel[qt][14 + kt];
      }
    }
  }
  __syncthreads();

  // ---- softmax over 392 ----
  {
    int wave = tid >> 6, lane = tid & 63;
    for (int row = wave * 4; row < wave * 4 + 4; ++row) {
      float m = -1e30f;
      for (int k = lane; k < LK; k += 64) m = fmaxf(m, sS[row][k]);
#pragma unroll
      for (int off = 32; off; off >>= 1) m = fmaxf(m, __shfl_xor(m, off, 64));
      float sum = 0.f;
      for (int k = lane; k < LK; k += 64) {
        float e = __expf(sS[row][k] - m);
        sS[row][k] = e;
        sum += e;
      }
#pragma unroll
      for (int off = 32; off; off >>= 1) sum += __shfl_xor(sum, off, 64);
      if (lane == 0) sSum[row] = sum;
    }
  }

  // ---- AV ----
  const float* vbase = vp + (size_t)bh * LK * HD;
  const int c0 = (tid & 15) * 4;
  float o[4] = {0.f, 0.f, 0.f, 0.f};
  for (int t0 = 0; t0 < LK; t0 += 64) {
    int tsz = min(64, LK - t0);
    __syncthreads();
    for (int e = tid * 4; e < tsz * 64; e += 1024) {
      int row = e >> 6, c = e & 63;
      *(float4*)&sK[row][c] = *(const float4*)(vbase + (size_t)(t0 + row) * HD + c);
    }
    __syncthreads();
#pragma unroll 4
    for (int kk = 0; kk < tsz; ++kk) {
      float p = sS[qt][t0 + kk];
      float4 vv = *(float4*)&sK[kk][c0];
      o[0] += p * vv.x; o[1] += p * vv.y; o[2] += p * vv.z; o[3] += p * vv.w;
    }
  }
  float inv = 1.f / sSum[qt];
  int qg = q0 + qt;
  float4 res = make_float4(o[0] * inv, o[1] * inv, o[2] * inv, o[3] * inv);
  *(float4*)(out + ((size_t)b * NQ + qg) * DIM + h * HD + c0) = res;
}

// ---------------- launch ----------------
extern "C" void kernel_launch(void* const* d_in, const int* in_sizes, int n_in,
                              void* d_out, int out_size, void* d_ws, size_t ws_size,
                              hipStream_t stream) {
  const float* x        = (const float*)d_in[0];
  const float* w_qkv    = (const float*)d_in[1];
  const float* b_qkv    = (const float*)d_in[2];
  const float* pool_q_w = (const float*)d_in[3];
  const float* pool_k_w = (const float*)d_in[4];
  const float* pool_v_w = (const float*)d_in[5];
  const float* norm_q_g = (const float*)d_in[6];
  const float* norm_q_b = (const float*)d_in[7];
  const float* norm_k_g = (const float*)d_in[8];
  const float* norm_k_b = (const float*)d_in[9];
  const float* norm_v_g = (const float*)d_in[10];
  const float* norm_v_b = (const float*)d_in[11];
  const float* rel_h    = (const float*)d_in[12];
  const float* rel_w    = (const float*)d_in[13];
  const float* rel_t    = (const float*)d_in[14];
  const float* w_proj   = (const float*)d_in[15];
  const float* b_proj   = (const float*)d_in[16];
  float* out = (float*)d_out;

  float* ws = (float*)d_ws;
  const size_t NQKV_THIRD = (size_t)BATCH * NH * NQ * HD;
  float* qkv  = ws;
  float* qpb  = ws + 3 * NQKV_THIRD;
  float* kpb  = qpb + NQKV_THIRD;
  float* vpb  = kpb + (size_t)BATCH * NH * LK * HD;
  float* relb = vpb + (size_t)BATCH * NH * LK * HD;
  float* attn_out = ws;  // reuse qkv region (free after pooling)

  const int M = BATCH * NQ;  // 12544

  gemm64<1><<<dim3(3 * DIM / 64, M / 64), 256, 0, stream>>>(
      x, w_qkv, b_qkv, qkv, M, 3 * DIM, DIM);

  {
    int wq = BATCH * NH * NQ;
    pool_ln<<<(wq + 3) / 4, 256, 0, stream>>>(qkv, qpb, pool_q_w, norm_q_g, norm_q_b,
                                              8, 14, 14, 1, 1);
    int wk = BATCH * NH * LK;
    pool_ln<<<(wk + 3) / 4, 256, 0, stream>>>(qkv + NQKV_THIRD, kpb, pool_k_w,
                                              norm_k_g, norm_k_b, 8, 7, 7, 2, 2);
    pool_ln<<<(wk + 3) / 4, 256, 0, stream>>>(qkv + 2 * NQKV_THIRD, vpb, pool_v_w,
                                              norm_v_g, norm_v_b, 8, 7, 7, 2, 2);
  }

  {
    int total = BATCH * NH * NQ * 22;
    rel_kernel<<<(total + 255) / 256, 256, 0, stream>>>(qpb, rel_h, rel_w, rel_t, relb);
  }

  attn_kernel<<<dim3(NQ / QT, NH, BATCH), 256, 0, stream>>>(qpb, kpb, vpb, relb, attn_out);

  gemm64<0><<<dim3(DIM / 64, M / 64), 256, 0, stream>>>(
      attn_out, w_proj, b_proj, out, M, DIM, DIM);
}

// Round 4
// 1293.816 us; speedup vs baseline: 9.0627x; 1.4806x over previous
//
#include <hip/hip_runtime.h>
#include <hip/hip_bf16.h>

#define BATCH 8
#define NH 12
#define DIM 768
#define HD 64
#define NQ 1568       // 8*14*14
#define TT 8
#define HH_ 14
#define WW_ 14
#define LK 392        // 8*7*7
#define SCALE 0.125f
#define EPS 1e-5f

typedef __bf16 bf16x8 __attribute__((ext_vector_type(8)));
typedef float f32x4 __attribute__((ext_vector_type(4)));

__device__ inline ushort f2bf(float f) {
  uint u = __float_as_uint(f);
  u += 0x7FFF + ((u >> 16) & 1);   // RNE
  return (ushort)(u >> 16);
}

// ---------------- cast fp32 -> bf16 (flat) ----------------
__global__ __launch_bounds__(256) void cast_bf16(const float* __restrict__ in,
                                                 ushort* __restrict__ outb, int n) {
  int i = (blockIdx.x * blockDim.x + threadIdx.x) * 4;
  if (i >= n) return;
  float4 v = *(const float4*)(in + i);
  ushort4 o = make_ushort4(f2bf(v.x), f2bf(v.y), f2bf(v.z), f2bf(v.w));
  *(ushort4*)(outb + i) = o;
}

// ---------------- transpose + cast: in[R][C] fp32 -> out[C][R] bf16 ----------------
__global__ __launch_bounds__(256) void transpose_cast(const float* __restrict__ in,
                                                      ushort* __restrict__ outb,
                                                      int R, int C) {
  __shared__ float tile[32][33];
  int tx = threadIdx.x & 31, ty = threadIdx.x >> 5;  // ty: 0..7
  int bx = blockIdx.x * 32;  // col base
  int by = blockIdx.y * 32;  // row base
#pragma unroll
  for (int r = 0; r < 4; ++r)
    tile[ty + r * 8][tx] = in[(size_t)(by + ty + r * 8) * C + bx + tx];
  __syncthreads();
#pragma unroll
  for (int r = 0; r < 4; ++r)
    outb[(size_t)(bx + ty + r * 8) * R + by + tx] = f2bf(tile[tx][ty + r * 8]);
}

// ---------------- bf16 MFMA GEMM: C = A[M][K] * Bt[N][K]^T + bias ----------------
// 128x128 tile, BK=32, 4 waves (2x2 of 64x64), 16x16x32 MFMA.
// EPI==0: out[row*N+col] (fp32).  EPI==1: qkv scatter.
template<int EPI>
__global__ __launch_bounds__(256) void gemm_mfma(const ushort* __restrict__ A,
                                                 const ushort* __restrict__ Bt,
                                                 const float* __restrict__ bias,
                                                 float* __restrict__ out,
                                                 int M, int N, int K) {
  __shared__ ushort As[128][40];  // row-major [m][k], pad 40 (80B rows, 16B-aligned frags)
  __shared__ ushort Bs[128][40];  // [n][k]
  const int tid = threadIdx.x;
  const int wave = tid >> 6, lane = tid & 63;
  const int quad = lane >> 4, l16 = lane & 15;
  const int row0 = blockIdx.y * 128;
  const int col0 = blockIdx.x * 128;
  const int wm = (wave & 1) * 64;
  const int wn = (wave >> 1) * 64;

  f32x4 acc[4][4];
#pragma unroll
  for (int i = 0; i < 4; ++i)
#pragma unroll
    for (int j = 0; j < 4; ++j) acc[i][j] = (f32x4){0.f, 0.f, 0.f, 0.f};

  const int ar = tid >> 2;        // 0..63
  const int ak = (tid & 3) * 8;   // 0,8,16,24

  for (int k0 = 0; k0 < K; k0 += 32) {
    uint4 a0 = *(const uint4*)(A + (size_t)(row0 + ar) * K + k0 + ak);
    uint4 a1 = *(const uint4*)(A + (size_t)(row0 + ar + 64) * K + k0 + ak);
    uint4 b0 = *(const uint4*)(Bt + (size_t)(col0 + ar) * K + k0 + ak);
    uint4 b1 = *(const uint4*)(Bt + (size_t)(col0 + ar + 64) * K + k0 + ak);
    __syncthreads();
    *(uint4*)&As[ar][ak] = a0;
    *(uint4*)&As[ar + 64][ak] = a1;
    *(uint4*)&Bs[ar][ak] = b0;
    *(uint4*)&Bs[ar + 64][ak] = b1;
    __syncthreads();
    bf16x8 af[4], bfr[4];
#pragma unroll
    for (int i = 0; i < 4; ++i)
      af[i] = *(const bf16x8*)&As[wm + i * 16 + l16][quad * 8];
#pragma unroll
    for (int j = 0; j < 4; ++j)
      bfr[j] = *(const bf16x8*)&Bs[wn + j * 16 + l16][quad * 8];
#pragma unroll
    for (int i = 0; i < 4; ++i)
#pragma unroll
      for (int j = 0; j < 4; ++j)
        acc[i][j] = __builtin_amdgcn_mfma_f32_16x16x32_bf16(af[i], bfr[j], acc[i][j], 0, 0, 0);
  }

#pragma unroll
  for (int i = 0; i < 4; ++i) {
#pragma unroll
    for (int j = 0; j < 4; ++j) {
      int col = col0 + wn + j * 16 + l16;
      float bv = bias[col];
#pragma unroll
      for (int r = 0; r < 4; ++r) {
        int row = row0 + wm + i * 16 + quad * 4 + r;
        float val = acc[i][j][r] + bv;
        if (EPI == 0) {
          out[(size_t)row * N + col] = val;
        } else {
          int b = row / NQ, nn = row % NQ;
          int s = col / DIM, rr = col % DIM;
          int h = rr >> 6, cc = rr & 63;
          out[((((size_t)s * BATCH + b) * NH + h) * NQ + nn) * HD + cc] = val;
        }
      }
    }
  }
}

// ---------------- depthwise 3x3x3 pool + LayerNorm(64) ----------------
__global__ __launch_bounds__(256) void pool_ln(const float* __restrict__ in,
                                               float* __restrict__ out,
                                               const float* __restrict__ wgt,
                                               const float* __restrict__ g,
                                               const float* __restrict__ bb,
                                               int OT, int OH, int OW,
                                               int sh, int sw) {
  const int OL = OT * OH * OW;
  const int wid = (blockIdx.x * blockDim.x + threadIdx.x) >> 6;
  const int lane = threadIdx.x & 63;
  const int total = BATCH * NH * OL;
  if (wid >= total) return;
  const int bh = wid / OL, opos = wid % OL;
  const int ot = opos / (OH * OW);
  const int r = opos % (OH * OW);
  const int oy = r / OW, ox = r % OW;
  const float* base = in + (size_t)bh * NQ * HD;
  const int c = lane;
  float acc = 0.f;
#pragma unroll
  for (int dt = 0; dt < 3; ++dt) {
    int it = ot + dt - 1;
    if (it < 0 || it >= TT) continue;
#pragma unroll
    for (int dy = 0; dy < 3; ++dy) {
      int iy = oy * sh + dy - 1;
      if (iy < 0 || iy >= HH_) continue;
#pragma unroll
      for (int dx = 0; dx < 3; ++dx) {
        int ix = ox * sw + dx - 1;
        if (ix < 0 || ix >= WW_) continue;
        int n = (it * HH_ + iy) * WW_ + ix;
        acc += base[(size_t)n * HD + c] * wgt[c * 27 + (dt * 3 + dy) * 3 + dx];
      }
    }
  }
  float s = acc;
#pragma unroll
  for (int off = 32; off; off >>= 1) s += __shfl_xor(s, off, 64);
  float mean = s * (1.f / 64.f);
  float d = acc - mean;
  float vs = d * d;
#pragma unroll
  for (int off = 32; off; off >>= 1) vs += __shfl_xor(vs, off, 64);
  float inv = rsqrtf(vs * (1.f / 64.f) + EPS);
  out[(size_t)wid * HD + c] = d * inv * g[c] + bb[c];
}

// ---------------- rel-pos bias precompute ----------------
__global__ __launch_bounds__(256) void rel_kernel(const float* __restrict__ qp,
                                                  const float* __restrict__ Rh,
                                                  const float* __restrict__ Rw,
                                                  const float* __restrict__ Rt,
                                                  float* __restrict__ rel) {
  const int idx = blockIdx.x * blockDim.x + threadIdx.x;
  const int total = BATCH * NH * NQ * 22;
  if (idx >= total) return;
  const int j = idx % 22;
  const int q = idx / 22;
  const int n = q % NQ;
  const int t = n / (HH_ * WW_);
  const int r = n % (HH_ * WW_);
  const int y = r / WW_, x = r % WW_;
  const float* R;
  if (j < 7)       R = Rh + (size_t)(y - 2 * j + 12) * HD;
  else if (j < 14) R = Rw + (size_t)(x - 2 * (j - 7) + 12) * HD;
  else             R = Rt + (size_t)(t - (j - 14) + 7) * HD;
  const float* qrow = qp + (size_t)q * HD;
  float acc = 0.f;
#pragma unroll 4
  for (int c = 0; c < HD; c += 4) {
    float4 a = *(const float4*)(qrow + c);
    float4 b = *(const float4*)(R + c);
    acc += a.x * b.x + a.y * b.y + a.z * b.z + a.w * b.w;
  }
  rel[(size_t)q * 24 + j] = acc;
}

// ---------------- fused attention: 16 queries per block (bf16 output) ----------------
#define QT 16
__global__ __launch_bounds__(256) void attn_kernel(const float* __restrict__ qp,
                                                   const float* __restrict__ kp,
                                                   const float* __restrict__ vp,
                                                   const float* __restrict__ rel,
                                                   ushort* __restrict__ outb) {
  __shared__ float sQ[QT][68];
  __shared__ float sK[64][68];
  __shared__ float sS[QT][404];
  __shared__ float sRel[QT][24];
  __shared__ float sSum[QT];
  const int qb = blockIdx.x;
  const int h = blockIdx.y;
  const int b = blockIdx.z;
  const int tid = threadIdx.x;
  const int bh = b * NH + h;
  const int q0 = qb * QT;

  {
    const float* qbase = qp + ((size_t)bh * NQ + q0) * HD;
    int e = tid * 4;
    int row = e >> 6, c = e & 63;
    *(float4*)&sQ[row][c] = *(const float4*)(qbase + row * HD + c);
  }
  for (int e = tid; e < QT * 22; e += 256) {
    int row = e / 22, j = e % 22;
    sRel[row][j] = rel[((size_t)bh * NQ + q0 + row) * 24 + j];
  }

  const float* kbase = kp + (size_t)bh * LK * HD;
  const int qt = tid >> 4;
  const int klane = tid & 15;

  // ---- QK^T + bias ----
  for (int t0 = 0; t0 < LK; t0 += 64) {
    int tsz = min(64, LK - t0);
    __syncthreads();
    for (int e = tid * 4; e < tsz * 64; e += 1024) {
      int row = e >> 6, c = e & 63;
      *(float4*)&sK[row][c] = *(const float4*)(kbase + (size_t)(t0 + row) * HD + c);
    }
    __syncthreads();
    float acc[4] = {0.f, 0.f, 0.f, 0.f};
    // bounded unroll — full unroll spilled (R1: 13.5 GB scratch traffic)
#pragma unroll 4
    for (int c = 0; c < HD; c += 4) {
      float4 qv = *(float4*)&sQ[qt][c];
#pragma unroll
      for (int ii = 0; ii < 4; ++ii) {
        int kk = klane + ii * 16;
        float4 kv = *(float4*)&sK[kk][c];
        acc[ii] += qv.x * kv.x + qv.y * kv.y + qv.z * kv.z + qv.w * kv.w;
      }
    }
#pragma unroll
    for (int ii = 0; ii < 4; ++ii) {
      int kk = klane + ii * 16;
      if (kk < tsz) {
        int kg = t0 + kk;
        int kt = kg / 49, kr = kg % 49, ky = kr / 7, kx = kr % 7;
        sS[qt][kg] = acc[ii] * SCALE + sRel[qt][ky] + sRel[qt][7 + kx] + sRel[qt][14 + kt];
      }
    }
  }
  __syncthreads();

  // ---- softmax over 392 ----
  {
    int wave = tid >> 6, lane = tid & 63;
    for (int row = wave * 4; row < wave * 4 + 4; ++row) {
      float m = -1e30f;
      for (int k = lane; k < LK; k += 64) m = fmaxf(m, sS[row][k]);
#pragma unroll
      for (int off = 32; off; off >>= 1) m = fmaxf(m, __shfl_xor(m, off, 64));
      float sum = 0.f;
      for (int k = lane; k < LK; k += 64) {
        float e = __expf(sS[row][k] - m);
        sS[row][k] = e;
        sum += e;
      }
#pragma unroll
      for (int off = 32; off; off >>= 1) sum += __shfl_xor(sum, off, 64);
      if (lane == 0) sSum[row] = sum;
    }
  }

  // ---- AV ----
  const float* vbase = vp + (size_t)bh * LK * HD;
  const int c0 = (tid & 15) * 4;
  float o[4] = {0.f, 0.f, 0.f, 0.f};
  for (int t0 = 0; t0 < LK; t0 += 64) {
    int tsz = min(64, LK - t0);
    __syncthreads();
    for (int e = tid * 4; e < tsz * 64; e += 1024) {
      int row = e >> 6, c = e & 63;
      *(float4*)&sK[row][c] = *(const float4*)(vbase + (size_t)(t0 + row) * HD + c);
    }
    __syncthreads();
#pragma unroll 4
    for (int kk = 0; kk < tsz; ++kk) {
      float p = sS[qt][t0 + kk];
      float4 vv = *(float4*)&sK[kk][c0];
      o[0] += p * vv.x; o[1] += p * vv.y; o[2] += p * vv.z; o[3] += p * vv.w;
    }
  }
  float inv = 1.f / sSum[qt];
  int qg = q0 + qt;
  ushort4 res = make_ushort4(f2bf(o[0] * inv), f2bf(o[1] * inv),
                             f2bf(o[2] * inv), f2bf(o[3] * inv));
  *(ushort4*)(outb + ((size_t)b * NQ + qg) * DIM + h * HD + c0) = res;
}

// ---------------- launch ----------------
extern "C" void kernel_launch(void* const* d_in, const int* in_sizes, int n_in,
                              void* d_out, int out_size, void* d_ws, size_t ws_size,
                              hipStream_t stream) {
  const float* x        = (const float*)d_in[0];
  const float* w_qkv    = (const float*)d_in[1];
  const float* b_qkv    = (const float*)d_in[2];
  const float* pool_q_w = (const float*)d_in[3];
  const float* pool_k_w = (const float*)d_in[4];
  const float* pool_v_w = (const float*)d_in[5];
  const float* norm_q_g = (const float*)d_in[6];
  const float* norm_q_b = (const float*)d_in[7];
  const float* norm_k_g = (const float*)d_in[8];
  const float* norm_k_b = (const float*)d_in[9];
  const float* norm_v_g = (const float*)d_in[10];
  const float* norm_v_b = (const float*)d_in[11];
  const float* rel_h    = (const float*)d_in[12];
  const float* rel_w    = (const float*)d_in[13];
  const float* rel_t    = (const float*)d_in[14];
  const float* w_proj   = (const float*)d_in[15];
  const float* b_proj   = (const float*)d_in[16];
  float* out = (float*)d_out;

  float* ws = (float*)d_ws;
  const size_t NT  = (size_t)BATCH * NH * NQ * HD;   // 9,633,792
  const size_t LKT = (size_t)BATCH * NH * LK * HD;   // 2,408,448
  const size_t RELN = (size_t)BATCH * NH * NQ * 24;  // 3,612,672

  float* qkv  = ws;                    // [0, 3NT)
  float* qpb  = ws + 3 * NT;           // [3NT, 4NT)
  float* kpb  = qpb + NT;
  float* vpb  = kpb + LKT;
  float* relb = vpb + LKT;
  ushort* wqkvT = (ushort*)(relb + RELN);          // 768*2304 bf16
  ushort* wprojT = wqkvT + (size_t)DIM * 3 * DIM;  // 768*768 bf16
  // overlays (stream-ordered):
  ushort* xb = (ushort*)qpb;        // x bf16, dead before pool writes qpb
  ushort* attn_outb = (ushort*)ws;  // overlays qkv region, dead after pooling

  const int M = BATCH * NQ;  // 12544

  // 0. casts / transposes
  {
    int n = M * DIM;
    cast_bf16<<<(n / 4 + 255) / 256, 256, 0, stream>>>(x, xb, n);
    transpose_cast<<<dim3(3 * DIM / 32, DIM / 32), 256, 0, stream>>>(w_qkv, wqkvT, DIM, 3 * DIM);
    transpose_cast<<<dim3(DIM / 32, DIM / 32), 256, 0, stream>>>(w_proj, wprojT, DIM, DIM);
  }

  // 1. QKV projection (bf16 MFMA) -> scattered fp32 [s][b][h][n][c]
  gemm_mfma<1><<<dim3(3 * DIM / 128, M / 128), 256, 0, stream>>>(
      xb, wqkvT, b_qkv, qkv, M, 3 * DIM, DIM);

  // 2. pool + LN
  {
    int wq = BATCH * NH * NQ;
    pool_ln<<<(wq + 3) / 4, 256, 0, stream>>>(qkv, qpb, pool_q_w, norm_q_g, norm_q_b,
                                              8, 14, 14, 1, 1);
    int wk = BATCH * NH * LK;
    pool_ln<<<(wk + 3) / 4, 256, 0, stream>>>(qkv + NT, kpb, pool_k_w,
                                              norm_k_g, norm_k_b, 8, 7, 7, 2, 2);
    pool_ln<<<(wk + 3) / 4, 256, 0, stream>>>(qkv + 2 * NT, vpb, pool_v_w,
                                              norm_v_g, norm_v_b, 8, 7, 7, 2, 2);
  }

  // 3. rel-pos dot products
  {
    int total = BATCH * NH * NQ * 22;
    rel_kernel<<<(total + 255) / 256, 256, 0, stream>>>(qpb, rel_h, rel_w, rel_t, relb);
  }

  // 4. fused attention -> bf16 [M][768]
  attn_kernel<<<dim3(NQ / QT, NH, BATCH), 256, 0, stream>>>(qpb, kpb, vpb, relb, attn_outb);

  // 5. output projection (bf16 MFMA)
  gemm_mfma<0><<<dim3(DIM / 128, M / 128), 256, 0, stream>>>(
      attn_outb, wprojT, b_proj, out, M, DIM, DIM);
}

// Round 5
// 885.643 us; speedup vs baseline: 13.2395x; 1.4609x over previous
//
#include <hip/hip_runtime.h>
#include <hip/hip_bf16.h>

#define BATCH 8
#define NH 12
#define DIM 768
#define HD 64
#define NQ 1568       // 8*14*14
#define TT 8
#define HH_ 14
#define WW_ 14
#define LK 392        // 8*7*7
#define SCALE 0.125f
#define EPS 1e-5f

typedef __bf16 bf16x8 __attribute__((ext_vector_type(8)));
typedef float f32x4 __attribute__((ext_vector_type(4)));

__device__ inline ushort f2bf(float f) {
  uint u = __float_as_uint(f);
  u += 0x7FFF + ((u >> 16) & 1);   // RNE
  return (ushort)(u >> 16);
}
__device__ inline float bfl(uint u) { return __uint_as_float(u << 16); }
__device__ inline float bfh(uint u) { return __uint_as_float(u & 0xffff0000u); }

// ---------------- cast fp32 -> bf16 (flat) ----------------
__global__ __launch_bounds__(256) void cast_bf16(const float* __restrict__ in,
                                                 ushort* __restrict__ outb, int n) {
  int i = (blockIdx.x * blockDim.x + threadIdx.x) * 4;
  if (i >= n) return;
  float4 v = *(const float4*)(in + i);
  ushort4 o = make_ushort4(f2bf(v.x), f2bf(v.y), f2bf(v.z), f2bf(v.w));
  *(ushort4*)(outb + i) = o;
}

// ---------------- transpose + cast: in[R][C] fp32 -> out[C][R] bf16 ----------------
__global__ __launch_bounds__(256) void transpose_cast(const float* __restrict__ in,
                                                      ushort* __restrict__ outb,
                                                      int R, int C) {
  __shared__ float tile[32][33];
  int tx = threadIdx.x & 31, ty = threadIdx.x >> 5;
  int bx = blockIdx.x * 32;
  int by = blockIdx.y * 32;
#pragma unroll
  for (int r = 0; r < 4; ++r)
    tile[ty + r * 8][tx] = in[(size_t)(by + ty + r * 8) * C + bx + tx];
  __syncthreads();
#pragma unroll
  for (int r = 0; r < 4; ++r)
    outb[(size_t)(bx + ty + r * 8) * R + by + tx] = f2bf(tile[tx][ty + r * 8]);
}

// ---------------- bf16 MFMA GEMM: C = A[M][K] * Bt[N][K]^T + bias ----------------
template<int EPI>
__global__ __launch_bounds__(256) void gemm_mfma(const ushort* __restrict__ A,
                                                 const ushort* __restrict__ Bt,
                                                 const float* __restrict__ bias,
                                                 float* __restrict__ out,
                                                 int M, int N, int K) {
  __shared__ ushort As[128][40];
  __shared__ ushort Bs[128][40];
  const int tid = threadIdx.x;
  const int wave = tid >> 6, lane = tid & 63;
  const int quad = lane >> 4, l16 = lane & 15;
  const int row0 = blockIdx.y * 128;
  const int col0 = blockIdx.x * 128;
  const int wm = (wave & 1) * 64;
  const int wn = (wave >> 1) * 64;

  f32x4 acc[4][4];
#pragma unroll
  for (int i = 0; i < 4; ++i)
#pragma unroll
    for (int j = 0; j < 4; ++j) acc[i][j] = (f32x4){0.f, 0.f, 0.f, 0.f};

  const int ar = tid >> 2;
  const int ak = (tid & 3) * 8;

  for (int k0 = 0; k0 < K; k0 += 32) {
    uint4 a0 = *(const uint4*)(A + (size_t)(row0 + ar) * K + k0 + ak);
    uint4 a1 = *(const uint4*)(A + (size_t)(row0 + ar + 64) * K + k0 + ak);
    uint4 b0 = *(const uint4*)(Bt + (size_t)(col0 + ar) * K + k0 + ak);
    uint4 b1 = *(const uint4*)(Bt + (size_t)(col0 + ar + 64) * K + k0 + ak);
    __syncthreads();
    *(uint4*)&As[ar][ak] = a0;
    *(uint4*)&As[ar + 64][ak] = a1;
    *(uint4*)&Bs[ar][ak] = b0;
    *(uint4*)&Bs[ar + 64][ak] = b1;
    __syncthreads();
    bf16x8 af[4], bfr[4];
#pragma unroll
    for (int i = 0; i < 4; ++i)
      af[i] = *(const bf16x8*)&As[wm + i * 16 + l16][quad * 8];
#pragma unroll
    for (int j = 0; j < 4; ++j)
      bfr[j] = *(const bf16x8*)&Bs[wn + j * 16 + l16][quad * 8];
#pragma unroll
    for (int i = 0; i < 4; ++i)
#pragma unroll
      for (int j = 0; j < 4; ++j)
        acc[i][j] = __builtin_amdgcn_mfma_f32_16x16x32_bf16(af[i], bfr[j], acc[i][j], 0, 0, 0);
  }

#pragma unroll
  for (int i = 0; i < 4; ++i) {
#pragma unroll
    for (int j = 0; j < 4; ++j) {
      int col = col0 + wn + j * 16 + l16;
      float bv = bias[col];
#pragma unroll
      for (int r = 0; r < 4; ++r) {
        int row = row0 + wm + i * 16 + quad * 4 + r;
        float val = acc[i][j][r] + bv;
        if (EPI == 0) {
          out[(size_t)row * N + col] = val;
        } else {
          int b = row / NQ, nn = row % NQ;
          int s = col / DIM, rr = col % DIM;
          int h = rr >> 6, cc = rr & 63;
          out[((((size_t)s * BATCH + b) * NH + h) * NQ + nn) * HD + cc] = val;
        }
      }
    }
  }
}

// ---------------- depthwise 3x3x3 pool + LayerNorm(64) -> bf16 ----------------
// VT==0: out[wid][c] row-major. VT==1: transposed out[bh][c][opos] (for AV B-operand).
template<int VT>
__global__ __launch_bounds__(256) void pool_ln(const float* __restrict__ in,
                                               ushort* __restrict__ out,
                                               const float* __restrict__ wgt,
                                               const float* __restrict__ g,
                                               const float* __restrict__ bb,
                                               int OT, int OH, int OW,
                                               int sh, int sw) {
  const int OL = OT * OH * OW;
  const int wid = (blockIdx.x * blockDim.x + threadIdx.x) >> 6;
  const int lane = threadIdx.x & 63;
  const int total = BATCH * NH * OL;
  if (wid >= total) return;
  const int bh = wid / OL, opos = wid % OL;
  const int ot = opos / (OH * OW);
  const int r = opos % (OH * OW);
  const int oy = r / OW, ox = r % OW;
  const float* base = in + (size_t)bh * NQ * HD;
  const int c = lane;
  float acc = 0.f;
#pragma unroll
  for (int dt = 0; dt < 3; ++dt) {
    int it = ot + dt - 1;
    if (it < 0 || it >= TT) continue;
#pragma unroll
    for (int dy = 0; dy < 3; ++dy) {
      int iy = oy * sh + dy - 1;
      if (iy < 0 || iy >= HH_) continue;
#pragma unroll
      for (int dx = 0; dx < 3; ++dx) {
        int ix = ox * sw + dx - 1;
        if (ix < 0 || ix >= WW_) continue;
        int n = (it * HH_ + iy) * WW_ + ix;
        acc += base[(size_t)n * HD + c] * wgt[c * 27 + (dt * 3 + dy) * 3 + dx];
      }
    }
  }
  float s = acc;
#pragma unroll
  for (int off = 32; off; off >>= 1) s += __shfl_xor(s, off, 64);
  float mean = s * (1.f / 64.f);
  float d = acc - mean;
  float vs = d * d;
#pragma unroll
  for (int off = 32; off; off >>= 1) vs += __shfl_xor(vs, off, 64);
  float inv = rsqrtf(vs * (1.f / 64.f) + EPS);
  float res = d * inv * g[c] + bb[c];
  if (VT == 0) out[(size_t)wid * HD + c] = f2bf(res);
  else         out[((size_t)bh * HD + c) * OL + opos] = f2bf(res);
}

// ---------------- rel-pos bias precompute (bf16 q) ----------------
__global__ __launch_bounds__(256) void rel_kernel(const ushort* __restrict__ qp,
                                                  const float* __restrict__ Rh,
                                                  const float* __restrict__ Rw,
                                                  const float* __restrict__ Rt,
                                                  float* __restrict__ rel) {
  const int idx = blockIdx.x * blockDim.x + threadIdx.x;
  const int total = BATCH * NH * NQ * 22;
  if (idx >= total) return;
  const int j = idx % 22;
  const int q = idx / 22;
  const int n = q % NQ;
  const int t = n / (HH_ * WW_);
  const int r = n % (HH_ * WW_);
  const int y = r / WW_, x = r % WW_;
  const float* R;
  if (j < 7)       R = Rh + (size_t)(y - 2 * j + 12) * HD;
  else if (j < 14) R = Rw + (size_t)(x - 2 * (j - 7) + 12) * HD;
  else             R = Rt + (size_t)(t - (j - 14) + 7) * HD;
  const ushort* qrow = qp + (size_t)q * HD;
  float acc = 0.f;
#pragma unroll 2
  for (int c = 0; c < HD; c += 8) {
    uint4 qa = *(const uint4*)(qrow + c);
    float4 r0 = *(const float4*)(R + c);
    float4 r1 = *(const float4*)(R + c + 4);
    acc += bfl(qa.x) * r0.x + bfh(qa.x) * r0.y + bfl(qa.y) * r0.z + bfh(qa.y) * r0.w;
    acc += bfl(qa.z) * r1.x + bfh(qa.z) * r1.y + bfl(qa.w) * r1.z + bfh(qa.w) * r1.w;
  }
  rel[(size_t)q * 24 + j] = acc;
}

// ---------------- MFMA attention: 16 queries/block, 4 waves ----------------
// S[16][420] fp32 in LDS (40KB total block LDS); P bf16 in-place over S.
__global__ __launch_bounds__(256) void attn_mfma(const ushort* __restrict__ qp,
                                                 const ushort* __restrict__ kp,
                                                 const ushort* __restrict__ vT,
                                                 const float* __restrict__ rel,
                                                 ushort* __restrict__ outb) {
  __shared__ ushort sQ[16][72];
  __shared__ ushort sK[64][72];     // also reused for V^T chunks
  __shared__ float sS[16][420];
  __shared__ float sRel[16][24];
  __shared__ float sSum[16];
  const int qb = blockIdx.x;       // 0..97
  const int bh = blockIdx.y;       // 0..95
  const int b = bh / NH, h = bh % NH;
  const int tid = threadIdx.x;
  const int w = tid >> 6, lane = tid & 63;
  const int quad = lane >> 4, l16 = lane & 15;
  const int q0 = qb * 16;

  // stage Q tile: 16x64 bf16 = 128 uint4
  if (tid < 128) {
    int row = tid >> 3, off = (tid & 7) * 8;
    *(uint4*)&sQ[row][off] = *(const uint4*)(qp + ((size_t)bh * NQ + q0 + row) * HD + off);
  }
  for (int e = tid; e < 16 * 22; e += 256) {
    int row = e / 22, j = e % 22;
    sRel[row][j] = rel[((size_t)bh * NQ + q0 + row) * 24 + j];
  }
  __syncthreads();

  // A fragments (Q) — fixed for whole QK^T phase. A[m=l16][k=quad*8+j]
  bf16x8 af0 = *(const bf16x8*)&sQ[l16][quad * 8];
  bf16x8 af1 = *(const bf16x8*)&sQ[l16][32 + quad * 8];

  f32x4 acc[7];
#pragma unroll
  for (int i = 0; i < 7; ++i) acc[i] = (f32x4){0.f, 0.f, 0.f, 0.f};

  const ushort* kbase = kp + (size_t)bh * LK * HD;

  // ---- QK^T: 7 chunks of 64 K-rows; wave w owns tiles tg with tg%4==w ----
  for (int c = 0; c < 7; ++c) {
    __syncthreads();
#pragma unroll
    for (int i = 0; i < 2; ++i) {
      int e = tid + i * 256;
      int row = e >> 3, off = (e & 7) * 8;
      int kr = c * 64 + row;
      uint4 val = make_uint4(0, 0, 0, 0);
      if (kr < LK) val = *(const uint4*)(kbase + (size_t)kr * HD + off);
      *(uint4*)&sK[row][off] = val;
    }
    __syncthreads();
#pragma unroll
    for (int j = 0; j < 4; ++j) {
      int tg = c * 4 + j;
      if (tg >= 25 || (tg & 3) != w) continue;
      int lrow = j * 16 + l16;
      bf16x8 b0 = *(const bf16x8*)&sK[lrow][quad * 8];
      bf16x8 b1 = *(const bf16x8*)&sK[lrow][32 + quad * 8];
      int ai = tg >> 2;
      acc[ai] = __builtin_amdgcn_mfma_f32_16x16x32_bf16(af0, b0, acc[ai], 0, 0, 0);
      acc[ai] = __builtin_amdgcn_mfma_f32_16x16x32_bf16(af1, b1, acc[ai], 0, 0, 0);
    }
  }

  // ---- S-write with scale + rel bias. C/D: col=l16 (k), row=quad*4+r (q) ----
#pragma unroll
  for (int ai = 0; ai < 7; ++ai) {
    int tg = ai * 4 + w;
    if (tg >= 25) break;
    int kg = tg * 16 + l16;
    if (kg < LK) {
      int kt = kg / 49, kr2 = kg % 49, ky = kr2 / 7, kx = kr2 % 7;
#pragma unroll
      for (int r = 0; r < 4; ++r) {
        int q = quad * 4 + r;
        sS[q][kg] = acc[ai][r] * SCALE + sRel[q][ky] + sRel[q][7 + kx] + sRel[q][14 + kt];
      }
    } else {
#pragma unroll
      for (int r = 0; r < 4; ++r) sS[quad * 4 + r][kg] = -1e30f;
    }
  }
  __syncthreads();

  // ---- softmax: wave w handles rows w*4..w*4+3; P bf16 written in place ----
  for (int row = w * 4; row < w * 4 + 4; ++row) {
    float m = -1e30f;
    for (int k = lane; k < LK; k += 64) m = fmaxf(m, sS[row][k]);
#pragma unroll
    for (int off = 32; off; off >>= 1) m = fmaxf(m, __shfl_xor(m, off, 64));
    float sum = 0.f;
    ushort* pr = (ushort*)&sS[row][0];
    for (int k = lane; k < 416; k += 64) {
      float e = 0.f;
      if (k < LK) { e = __expf(sS[row][k] - m); sum += e; }
      pr[k] = f2bf(e);     // byte 2k writes never pass byte 4k reads (DS in-order)
    }
#pragma unroll
    for (int off = 32; off; off >>= 1) sum += __shfl_xor(sum, off, 64);
    if (lane == 0) sSum[row] = sum;
  }

  // ---- AV: O[16][64] = P[16][416] x V^T; wave w -> output channels w*16..+15 ----
  f32x4 oacc = (f32x4){0.f, 0.f, 0.f, 0.f};
  const ushort* vbase = vT + (size_t)bh * HD * LK;   // [c][kpos]
  for (int c = 0; c < 7; ++c) {
    __syncthreads();
#pragma unroll
    for (int i = 0; i < 2; ++i) {
      int e = tid + i * 256;
      int row = e >> 3, off = (e & 7) * 8;  // row = channel, off = kpos offset
      int kr = c * 64 + off;
      uint4 val = make_uint4(0, 0, 0, 0);
      if (kr + 7 < LK) val = *(const uint4*)(vbase + (size_t)row * LK + kr);
      *(uint4*)&sK[row][off] = val;
    }
    __syncthreads();
    int ksteps = (c == 6) ? 1 : 2;
    for (int s = 0; s < ksteps; ++s) {
      int kb = c * 64 + s * 32;
      bf16x8 pa = *(const bf16x8*)((const ushort*)&sS[l16][0] + kb + quad * 8);
      bf16x8 vb = *(const bf16x8*)&sK[w * 16 + l16][s * 32 + quad * 8];
      oacc = __builtin_amdgcn_mfma_f32_16x16x32_bf16(pa, vb, oacc, 0, 0, 0);
    }
  }

#pragma unroll
  for (int r = 0; r < 4; ++r) {
    int q = quad * 4 + r;
    float val = oacc[r] / sSum[q];
    outb[((size_t)b * NQ + q0 + q) * DIM + h * HD + w * 16 + l16] = f2bf(val);
  }
}

// ---------------- launch ----------------
extern "C" void kernel_launch(void* const* d_in, const int* in_sizes, int n_in,
                              void* d_out, int out_size, void* d_ws, size_t ws_size,
                              hipStream_t stream) {
  const float* x        = (const float*)d_in[0];
  const float* w_qkv    = (const float*)d_in[1];
  const float* b_qkv    = (const float*)d_in[2];
  const float* pool_q_w = (const float*)d_in[3];
  const float* pool_k_w = (const float*)d_in[4];
  const float* pool_v_w = (const float*)d_in[5];
  const float* norm_q_g = (const float*)d_in[6];
  const float* norm_q_b = (const float*)d_in[7];
  const float* norm_k_g = (const float*)d_in[8];
  const float* norm_k_b = (const float*)d_in[9];
  const float* norm_v_g = (const float*)d_in[10];
  const float* norm_v_b = (const float*)d_in[11];
  const float* rel_h    = (const float*)d_in[12];
  const float* rel_w    = (const float*)d_in[13];
  const float* rel_t    = (const float*)d_in[14];
  const float* w_proj   = (const float*)d_in[15];
  const float* b_proj   = (const float*)d_in[16];
  float* out = (float*)d_out;

  float* ws = (float*)d_ws;
  const size_t NT  = (size_t)BATCH * NH * NQ * HD;   // 9,633,792
  const size_t LKT = (size_t)BATCH * NH * LK * HD;   // 2,408,448
  const size_t RELN = (size_t)BATCH * NH * NQ * 24;

  float*  qkv  = ws;                          // 3NT fp32
  ushort* qpb  = (ushort*)(ws + 3 * NT);      // NT bf16
  ushort* kpb  = qpb + NT;                    // LKT bf16
  ushort* vTb  = kpb + LKT;                   // LKT bf16 (transposed [bh][c][kpos])
  float*  relb = (float*)(vTb + LKT);         // RELN fp32 (offset stays 4B-aligned)
  ushort* wqkvT = (ushort*)(relb + RELN);
  ushort* wprojT = wqkvT + (size_t)DIM * 3 * DIM;
  ushort* xb = qpb;                 // overlay: dead before pool writes qpb
  ushort* attn_outb = (ushort*)ws;  // overlay: qkv dead after pooling

  const int M = BATCH * NQ;  // 12544

  // 0. casts / transposes
  {
    int n = M * DIM;
    cast_bf16<<<(n / 4 + 255) / 256, 256, 0, stream>>>(x, xb, n);
    transpose_cast<<<dim3(3 * DIM / 32, DIM / 32), 256, 0, stream>>>(w_qkv, wqkvT, DIM, 3 * DIM);
    transpose_cast<<<dim3(DIM / 32, DIM / 32), 256, 0, stream>>>(w_proj, wprojT, DIM, DIM);
  }

  // 1. QKV projection (bf16 MFMA) -> scattered fp32 [s][b][h][n][c]
  gemm_mfma<1><<<dim3(3 * DIM / 128, M / 128), 256, 0, stream>>>(
      xb, wqkvT, b_qkv, qkv, M, 3 * DIM, DIM);

  // 2. pool + LN -> bf16 (q,k row-major; v transposed)
  {
    int wq = BATCH * NH * NQ;
    pool_ln<0><<<(wq + 3) / 4, 256, 0, stream>>>(qkv, qpb, pool_q_w, norm_q_g, norm_q_b,
                                                 8, 14, 14, 1, 1);
    int wk = BATCH * NH * LK;
    pool_ln<0><<<(wk + 3) / 4, 256, 0, stream>>>(qkv + NT, kpb, pool_k_w,
                                                 norm_k_g, norm_k_b, 8, 7, 7, 2, 2);
    pool_ln<1><<<(wk + 3) / 4, 256, 0, stream>>>(qkv + 2 * NT, vTb, pool_v_w,
                                                 norm_v_g, norm_v_b, 8, 7, 7, 2, 2);
  }

  // 3. rel-pos dot products
  {
    int total = BATCH * NH * NQ * 22;
    rel_kernel<<<(total + 255) / 256, 256, 0, stream>>>(qpb, rel_h, rel_w, rel_t, relb);
  }

  // 4. MFMA attention -> bf16 [M][768]
  attn_mfma<<<dim3(NQ / 16, BATCH * NH), 256, 0, stream>>>(qpb, kpb, vTb, relb, attn_outb);

  // 5. output projection (bf16 MFMA)
  gemm_mfma<0><<<dim3(DIM / 128, M / 128), 256, 0, stream>>>(
      attn_outb, wprojT, b_proj, out, M, DIM, DIM);
}

// Round 6
// 642.589 us; speedup vs baseline: 18.2473x; 1.3782x over previous
//
#include <hip/hip_runtime.h>
#include <hip/hip_bf16.h>

#define BATCH 8
#define NH 12
#define DIM 768
#define HD 64
#define NQ 1568       // 8*14*14
#define TT 8
#define HH_ 14
#define WW_ 14
#define LK 392        // 8*7*7
#define SCALE 0.125f
#define EPS 1e-5f

// padded pool-input layout: [s][bh][pt 0..9][py 0..15][px 0..15][c]
#define PT 10
#define PPLANE 256            // 16*16
#define PVOL 2560             // PT*PPLANE
#define PS ((size_t)BATCH * NH * PVOL * HD)   // elems per s-third

typedef __bf16 bf16x8 __attribute__((ext_vector_type(8)));
typedef float f32x4 __attribute__((ext_vector_type(4)));

__device__ inline ushort f2bf(float f) {
  uint u = __float_as_uint(f);
  u += 0x7FFF + ((u >> 16) & 1);   // RNE
  return (ushort)(u >> 16);
}
__device__ inline float bf2f(ushort v) { return __uint_as_float((uint)v << 16); }
__device__ inline float bfl(uint u) { return __uint_as_float(u << 16); }
__device__ inline float bfh(uint u) { return __uint_as_float(u & 0xffff0000u); }

// ---------------- zero fill (uint4 grid-stride) ----------------
__global__ __launch_bounds__(256) void zero_kernel(uint4* __restrict__ p, int n16) {
  int i = blockIdx.x * 256 + threadIdx.x;
  int stride = gridDim.x * 256;
  for (; i < n16; i += stride) p[i] = make_uint4(0, 0, 0, 0);
}

// ---------------- cast fp32 -> bf16 (flat) ----------------
__global__ __launch_bounds__(256) void cast_bf16(const float* __restrict__ in,
                                                 ushort* __restrict__ outb, int n) {
  int i = (blockIdx.x * blockDim.x + threadIdx.x) * 4;
  if (i >= n) return;
  float4 v = *(const float4*)(in + i);
  ushort4 o = make_ushort4(f2bf(v.x), f2bf(v.y), f2bf(v.z), f2bf(v.w));
  *(ushort4*)(outb + i) = o;
}

// ---------------- transpose + cast: in[R][C] fp32 -> out[C][R] bf16 ----------------
__global__ __launch_bounds__(256) void transpose_cast(const float* __restrict__ in,
                                                      ushort* __restrict__ outb,
                                                      int R, int C) {
  __shared__ float tile[32][33];
  int tx = threadIdx.x & 31, ty = threadIdx.x >> 5;
  int bx = blockIdx.x * 32;
  int by = blockIdx.y * 32;
#pragma unroll
  for (int r = 0; r < 4; ++r)
    tile[ty + r * 8][tx] = in[(size_t)(by + ty + r * 8) * C + bx + tx];
  __syncthreads();
#pragma unroll
  for (int r = 0; r < 4; ++r)
    outb[(size_t)(bx + ty + r * 8) * R + by + tx] = f2bf(tile[tx][ty + r * 8]);
}

// ---------------- pool-weight transpose: [c][27] -> [tap][c], 3 tensors ----------------
__global__ __launch_bounds__(256) void wpool_transpose(const float* __restrict__ wq,
                                                       const float* __restrict__ wk,
                                                       const float* __restrict__ wv,
                                                       float* __restrict__ wT) {
  int i = blockIdx.x * blockDim.x + threadIdx.x;
  if (i >= 3 * 27 * 64) return;
  int s = i / (27 * 64), r = i % (27 * 64), tap = r / 64, c = r % 64;
  const float* src = (s == 0) ? wq : ((s == 1) ? wk : wv);
  wT[i] = src[c * 27 + tap];
}

// ---------------- bf16 MFMA GEMM: C = A[M][K] * Bt[N][K]^T + bias ----------------
// EPI==0: fp32 out[row*N+col]. EPI==1: bf16 scatter into padded pool layout.
template<int EPI>
__global__ __launch_bounds__(256) void gemm_mfma(const ushort* __restrict__ A,
                                                 const ushort* __restrict__ Bt,
                                                 const float* __restrict__ bias,
                                                 float* __restrict__ outf,
                                                 ushort* __restrict__ outp,
                                                 int M, int N, int K) {
  __shared__ ushort As[128][40];
  __shared__ ushort Bs[128][40];
  const int tid = threadIdx.x;
  const int wave = tid >> 6, lane = tid & 63;
  const int quad = lane >> 4, l16 = lane & 15;
  const int row0 = blockIdx.y * 128;
  const int col0 = blockIdx.x * 128;
  const int wm = (wave & 1) * 64;
  const int wn = (wave >> 1) * 64;

  f32x4 acc[4][4];
#pragma unroll
  for (int i = 0; i < 4; ++i)
#pragma unroll
    for (int j = 0; j < 4; ++j) acc[i][j] = (f32x4){0.f, 0.f, 0.f, 0.f};

  const int ar = tid >> 2;
  const int ak = (tid & 3) * 8;

  for (int k0 = 0; k0 < K; k0 += 32) {
    uint4 a0 = *(const uint4*)(A + (size_t)(row0 + ar) * K + k0 + ak);
    uint4 a1 = *(const uint4*)(A + (size_t)(row0 + ar + 64) * K + k0 + ak);
    uint4 b0 = *(const uint4*)(Bt + (size_t)(col0 + ar) * K + k0 + ak);
    uint4 b1 = *(const uint4*)(Bt + (size_t)(col0 + ar + 64) * K + k0 + ak);
    __syncthreads();
    *(uint4*)&As[ar][ak] = a0;
    *(uint4*)&As[ar + 64][ak] = a1;
    *(uint4*)&Bs[ar][ak] = b0;
    *(uint4*)&Bs[ar + 64][ak] = b1;
    __syncthreads();
    bf16x8 af[4], bfr[4];
#pragma unroll
    for (int i = 0; i < 4; ++i)
      af[i] = *(const bf16x8*)&As[wm + i * 16 + l16][quad * 8];
#pragma unroll
    for (int j = 0; j < 4; ++j)
      bfr[j] = *(const bf16x8*)&Bs[wn + j * 16 + l16][quad * 8];
#pragma unroll
    for (int i = 0; i < 4; ++i)
#pragma unroll
      for (int j = 0; j < 4; ++j)
        acc[i][j] = __builtin_amdgcn_mfma_f32_16x16x32_bf16(af[i], bfr[j], acc[i][j], 0, 0, 0);
  }

#pragma unroll
  for (int i = 0; i < 4; ++i) {
#pragma unroll
    for (int j = 0; j < 4; ++j) {
      int col = col0 + wn + j * 16 + l16;
      float bv = bias[col];
#pragma unroll
      for (int r = 0; r < 4; ++r) {
        int row = row0 + wm + i * 16 + quad * 4 + r;
        float val = acc[i][j][r] + bv;
        if (EPI == 0) {
          outf[(size_t)row * N + col] = val;
        } else {
          int b = row / NQ, nn = row % NQ;
          int s = col / DIM, rr = col % DIM;
          int h = rr >> 6, cc = rr & 63;
          int t = nn / 196, r2 = nn % 196, y = r2 / 14, xx = r2 % 14;
          size_t pidx = (((size_t)s * BATCH * NH + b * NH + h) * PVOL
                         + (t + 1) * PPLANE + (y + 1) * 16 + (xx + 1)) * (size_t)HD + cc;
          outp[pidx] = f2bf(val);
        }
      }
    }
  }
}

// ---------------- padded depthwise pool + LayerNorm(64) -> bf16 ----------------
// input: padded bf16 [bh][pt][py][px][c]; no bounds checks (halo = zeros).
// SW: spatial stride (t-stride is 1). VT==1: transposed out [bh][c][opos].
template<int SW, int VT>
__global__ __launch_bounds__(256) void pool_ln_pad(const ushort* __restrict__ in,
                                                   ushort* __restrict__ out,
                                                   const float* __restrict__ wT,
                                                   const float* __restrict__ g,
                                                   const float* __restrict__ bb,
                                                   int OH, int OW) {
  const int OL = 8 * OH * OW;
  const int wid = (blockIdx.x * blockDim.x + threadIdx.x) >> 6;
  const int lane = threadIdx.x & 63;
  const int total = BATCH * NH * OL;
  if (wid >= total) return;
  const int bh = wid / OL, opos = wid % OL;
  const int ot = opos / (OH * OW);
  const int r = opos % (OH * OW);
  const int oy = r / OW, ox = r % OW;
  const int c = lane;
  const ushort* base = in + ((size_t)bh * PVOL + ot * PPLANE + oy * SW * 16 + ox * SW) * HD + c;

  // 27 unconditional loads (independent -> batched), then FMA chain
  float v[27], wv[27];
#pragma unroll
  for (int dt = 0; dt < 3; ++dt)
#pragma unroll
    for (int dy = 0; dy < 3; ++dy)
#pragma unroll
      for (int dx = 0; dx < 3; ++dx) {
        int i = (dt * 3 + dy) * 3 + dx;
        v[i] = bf2f(base[(size_t)(dt * PPLANE + dy * 16 + dx) * HD]);
        wv[i] = wT[i * 64 + c];
      }
  float acc = 0.f;
#pragma unroll
  for (int i = 0; i < 27; ++i) acc += v[i] * wv[i];

  float s = acc;
#pragma unroll
  for (int off = 32; off; off >>= 1) s += __shfl_xor(s, off, 64);
  float mean = s * (1.f / 64.f);
  float d = acc - mean;
  float vs = d * d;
#pragma unroll
  for (int off = 32; off; off >>= 1) vs += __shfl_xor(vs, off, 64);
  float inv = rsqrtf(vs * (1.f / 64.f) + EPS);
  float res = d * inv * g[c] + bb[c];
  if (VT == 0) out[(size_t)wid * HD + c] = f2bf(res);
  else         out[((size_t)bh * HD + c) * OL + opos] = f2bf(res);
}

// ---------------- rel-pos bias precompute (bf16 q) ----------------
__global__ __launch_bounds__(256) void rel_kernel(const ushort* __restrict__ qp,
                                                  const float* __restrict__ Rh,
                                                  const float* __restrict__ Rw,
                                                  const float* __restrict__ Rt,
                                                  float* __restrict__ rel) {
  const int idx = blockIdx.x * blockDim.x + threadIdx.x;
  const int total = BATCH * NH * NQ * 22;
  if (idx >= total) return;
  const int j = idx % 22;
  const int q = idx / 22;
  const int n = q % NQ;
  const int t = n / (HH_ * WW_);
  const int r = n % (HH_ * WW_);
  const int y = r / WW_, x = r % WW_;
  const float* R;
  if (j < 7)       R = Rh + (size_t)(y - 2 * j + 12) * HD;
  else if (j < 14) R = Rw + (size_t)(x - 2 * (j - 7) + 12) * HD;
  else             R = Rt + (size_t)(t - (j - 14) + 7) * HD;
  const ushort* qrow = qp + (size_t)q * HD;
  float acc = 0.f;
#pragma unroll 2
  for (int c = 0; c < HD; c += 8) {
    uint4 qa = *(const uint4*)(qrow + c);
    float4 r0 = *(const float4*)(R + c);
    float4 r1 = *(const float4*)(R + c + 4);
    acc += bfl(qa.x) * r0.x + bfh(qa.x) * r0.y + bfl(qa.y) * r0.z + bfh(qa.y) * r0.w;
    acc += bfl(qa.z) * r1.x + bfh(qa.z) * r1.y + bfl(qa.w) * r1.z + bfh(qa.w) * r1.w;
  }
  rel[(size_t)q * 24 + j] = acc;
}

// ---------------- MFMA attention: 16 queries/block, 4 waves ----------------
__global__ __launch_bounds__(256) void attn_mfma(const ushort* __restrict__ qp,
                                                 const ushort* __restrict__ kp,
                                                 const ushort* __restrict__ vT,
                                                 const float* __restrict__ rel,
                                                 ushort* __restrict__ outb) {
  __shared__ ushort sQ[16][72];
  __shared__ ushort sK[64][72];
  __shared__ float sS[16][420];
  __shared__ float sRel[16][24];
  __shared__ float sSum[16];
  const int qb = blockIdx.x;
  const int bh = blockIdx.y;
  const int b = bh / NH, h = bh % NH;
  const int tid = threadIdx.x;
  const int w = tid >> 6, lane = tid & 63;
  const int quad = lane >> 4, l16 = lane & 15;
  const int q0 = qb * 16;

  if (tid < 128) {
    int row = tid >> 3, off = (tid & 7) * 8;
    *(uint4*)&sQ[row][off] = *(const uint4*)(qp + ((size_t)bh * NQ + q0 + row) * HD + off);
  }
  for (int e = tid; e < 16 * 22; e += 256) {
    int row = e / 22, j = e % 22;
    sRel[row][j] = rel[((size_t)bh * NQ + q0 + row) * 24 + j];
  }
  __syncthreads();

  bf16x8 af0 = *(const bf16x8*)&sQ[l16][quad * 8];
  bf16x8 af1 = *(const bf16x8*)&sQ[l16][32 + quad * 8];

  f32x4 acc[7];
#pragma unroll
  for (int i = 0; i < 7; ++i) acc[i] = (f32x4){0.f, 0.f, 0.f, 0.f};

  const ushort* kbase = kp + (size_t)bh * LK * HD;

  for (int c = 0; c < 7; ++c) {
    __syncthreads();
#pragma unroll
    for (int i = 0; i < 2; ++i) {
      int e = tid + i * 256;
      int row = e >> 3, off = (e & 7) * 8;
      int kr = c * 64 + row;
      uint4 val = make_uint4(0, 0, 0, 0);
      if (kr < LK) val = *(const uint4*)(kbase + (size_t)kr * HD + off);
      *(uint4*)&sK[row][off] = val;
    }
    __syncthreads();
#pragma unroll
    for (int j = 0; j < 4; ++j) {
      int tg = c * 4 + j;
      if (tg >= 25 || (tg & 3) != w) continue;
      int lrow = j * 16 + l16;
      bf16x8 b0 = *(const bf16x8*)&sK[lrow][quad * 8];
      bf16x8 b1 = *(const bf16x8*)&sK[lrow][32 + quad * 8];
      int ai = tg >> 2;
      acc[ai] = __builtin_amdgcn_mfma_f32_16x16x32_bf16(af0, b0, acc[ai], 0, 0, 0);
      acc[ai] = __builtin_amdgcn_mfma_f32_16x16x32_bf16(af1, b1, acc[ai], 0, 0, 0);
    }
  }

#pragma unroll
  for (int ai = 0; ai < 7; ++ai) {
    int tg = ai * 4 + w;
    if (tg >= 25) break;
    int kg = tg * 16 + l16;
    if (kg < LK) {
      int kt = kg / 49, kr2 = kg % 49, ky = kr2 / 7, kx = kr2 % 7;
#pragma unroll
      for (int r = 0; r < 4; ++r) {
        int q = quad * 4 + r;
        sS[q][kg] = acc[ai][r] * SCALE + sRel[q][ky] + sRel[q][7 + kx] + sRel[q][14 + kt];
      }
    } else {
#pragma unroll
      for (int r = 0; r < 4; ++r) sS[quad * 4 + r][kg] = -1e30f;
    }
  }
  __syncthreads();

  for (int row = w * 4; row < w * 4 + 4; ++row) {
    float m = -1e30f;
    for (int k = lane; k < LK; k += 64) m = fmaxf(m, sS[row][k]);
#pragma unroll
    for (int off = 32; off; off >>= 1) m = fmaxf(m, __shfl_xor(m, off, 64));
    float sum = 0.f;
    ushort* pr = (ushort*)&sS[row][0];
    for (int k = lane; k < 416; k += 64) {
      float e = 0.f;
      if (k < LK) { e = __expf(sS[row][k] - m); sum += e; }
      pr[k] = f2bf(e);
    }
#pragma unroll
    for (int off = 32; off; off >>= 1) sum += __shfl_xor(sum, off, 64);
    if (lane == 0) sSum[row] = sum;
  }

  f32x4 oacc = (f32x4){0.f, 0.f, 0.f, 0.f};
  const ushort* vbase = vT + (size_t)bh * HD * LK;
  for (int c = 0; c < 7; ++c) {
    __syncthreads();
#pragma unroll
    for (int i = 0; i < 2; ++i) {
      int e = tid + i * 256;
      int row = e >> 3, off = (e & 7) * 8;
      int kr = c * 64 + off;
      uint4 val = make_uint4(0, 0, 0, 0);
      if (kr + 7 < LK) val = *(const uint4*)(vbase + (size_t)row * LK + kr);
      *(uint4*)&sK[row][off] = val;
    }
    __syncthreads();
    int ksteps = (c == 6) ? 1 : 2;
    for (int s = 0; s < ksteps; ++s) {
      int kb = c * 64 + s * 32;
      bf16x8 pa = *(const bf16x8*)((const ushort*)&sS[l16][0] + kb + quad * 8);
      bf16x8 vb = *(const bf16x8*)&sK[w * 16 + l16][s * 32 + quad * 8];
      oacc = __builtin_amdgcn_mfma_f32_16x16x32_bf16(pa, vb, oacc, 0, 0, 0);
    }
  }

#pragma unroll
  for (int r = 0; r < 4; ++r) {
    int q = quad * 4 + r;
    float val = oacc[r] / sSum[q];
    outb[((size_t)b * NQ + q0 + q) * DIM + h * HD + w * 16 + l16] = f2bf(val);
  }
}

// ---------------- launch ----------------
extern "C" void kernel_launch(void* const* d_in, const int* in_sizes, int n_in,
                              void* d_out, int out_size, void* d_ws, size_t ws_size,
                              hipStream_t stream) {
  const float* x        = (const float*)d_in[0];
  const float* w_qkv    = (const float*)d_in[1];
  const float* b_qkv    = (const float*)d_in[2];
  const float* pool_q_w = (const float*)d_in[3];
  const float* pool_k_w = (const float*)d_in[4];
  const float* pool_v_w = (const float*)d_in[5];
  const float* norm_q_g = (const float*)d_in[6];
  const float* norm_q_b = (const float*)d_in[7];
  const float* norm_k_g = (const float*)d_in[8];
  const float* norm_k_b = (const float*)d_in[9];
  const float* norm_v_g = (const float*)d_in[10];
  const float* norm_v_b = (const float*)d_in[11];
  const float* rel_h    = (const float*)d_in[12];
  const float* rel_w    = (const float*)d_in[13];
  const float* rel_t    = (const float*)d_in[14];
  const float* w_proj   = (const float*)d_in[15];
  const float* b_proj   = (const float*)d_in[16];
  float* out = (float*)d_out;

  const size_t NT  = (size_t)BATCH * NH * NQ * HD;   // 9,633,792
  const size_t LKT = (size_t)BATCH * NH * LK * HD;   // 2,408,448
  const size_t RELN = (size_t)BATCH * NH * NQ * 24;

  ushort* padQ = (ushort*)d_ws;                 // 3*PS bf16 (padded pool input)
  ushort* qpb  = padQ + 3 * PS;                 // NT bf16
  ushort* kpb  = qpb + NT;                      // LKT bf16
  ushort* vTb  = kpb + LKT;                     // LKT bf16 (transposed [bh][c][kpos])
  float*  relb = (float*)(vTb + LKT);           // RELN fp32
  ushort* wqkvT = (ushort*)(relb + RELN);
  ushort* wprojT = wqkvT + (size_t)DIM * 3 * DIM;
  float*  wpoolT = (float*)(wprojT + (size_t)DIM * DIM);  // 3*27*64 fp32
  ushort* xb = qpb;                   // overlay: dead before pool writes qpb
  ushort* attn_outb = padQ;           // overlay: padQ dead after pools

  const int M = BATCH * NQ;  // 12544

  // 0a. zero padded buffer (halo must be 0 for conv zero-padding semantics)
  zero_kernel<<<2048, 256, 0, stream>>>((uint4*)padQ, (int)(3 * PS * 2 / 16));
  // 0b. casts / transposes
  {
    int n = M * DIM;
    cast_bf16<<<(n / 4 + 255) / 256, 256, 0, stream>>>(x, xb, n);
    transpose_cast<<<dim3(3 * DIM / 32, DIM / 32), 256, 0, stream>>>(w_qkv, wqkvT, DIM, 3 * DIM);
    transpose_cast<<<dim3(DIM / 32, DIM / 32), 256, 0, stream>>>(w_proj, wprojT, DIM, DIM);
    wpool_transpose<<<(3 * 27 * 64 + 255) / 256, 256, 0, stream>>>(
        pool_q_w, pool_k_w, pool_v_w, wpoolT);
  }

  // 1. QKV projection -> bf16 scatter into padded layout
  gemm_mfma<1><<<dim3(3 * DIM / 128, M / 128), 256, 0, stream>>>(
      xb, wqkvT, b_qkv, nullptr, padQ, M, 3 * DIM, DIM);

  // 2. pool + LN -> bf16 (q,k row-major; v transposed)
  {
    int wq = BATCH * NH * NQ;
    pool_ln_pad<1, 0><<<(wq + 3) / 4, 256, 0, stream>>>(
        padQ, qpb, wpoolT, norm_q_g, norm_q_b, 14, 14);
    int wk = BATCH * NH * LK;
    pool_ln_pad<2, 0><<<(wk + 3) / 4, 256, 0, stream>>>(
        padQ + PS, kpb, wpoolT + 27 * 64, norm_k_g, norm_k_b, 7, 7);
    pool_ln_pad<2, 1><<<(wk + 3) / 4, 256, 0, stream>>>(
        padQ + 2 * PS, vTb, wpoolT + 2 * 27 * 64, norm_v_g, norm_v_b, 7, 7);
  }

  // 3. rel-pos dot products
  {
    int total = BATCH * NH * NQ * 22;
    rel_kernel<<<(total + 255) / 256, 256, 0, stream>>>(qpb, rel_h, rel_w, rel_t, relb);
  }

  // 4. MFMA attention -> bf16 [M][768] (overlays padQ, dead after pools)
  attn_mfma<<<dim3(NQ / 16, BATCH * NH), 256, 0, stream>>>(qpb, kpb, vTb, relb, attn_outb);

  // 5. output projection
  gemm_mfma<0><<<dim3(DIM / 128, M / 128), 256, 0, stream>>>(
      attn_outb, wprojT, b_proj, out, nullptr, M, DIM, DIM);
}

// Round 7
// 614.656 us; speedup vs baseline: 19.0765x; 1.0454x over previous
//
#include <hip/hip_runtime.h>
#include <hip/hip_bf16.h>

#define BATCH 8
#define NH 12
#define DIM 768
#define HD 64
#define NQ 1568       // 8*14*14
#define TT 8
#define HH_ 14
#define WW_ 14
#define LK 392        // 8*7*7
#define SCALE 0.125f
#define EPS 1e-5f

// padded pool-input layout: [s][bh][pt 0..9][py 0..15][px 0..15][c]
#define PT 10
#define PPLANE 256            // 16*16
#define PVOL 2560             // PT*PPLANE
#define PS ((size_t)BATCH * NH * PVOL * HD)   // elems per s-third

typedef __bf16 bf16x8 __attribute__((ext_vector_type(8)));
typedef float f32x4 __attribute__((ext_vector_type(4)));

__device__ inline ushort f2bf(float f) {
  uint u = __float_as_uint(f);
  u += 0x7FFF + ((u >> 16) & 1);   // RNE
  return (ushort)(u >> 16);
}
__device__ inline float bf2f(ushort v) { return __uint_as_float((uint)v << 16); }
__device__ inline float bfl(uint u) { return __uint_as_float(u << 16); }
__device__ inline float bfh(uint u) { return __uint_as_float(u & 0xffff0000u); }

// ---------------- zero fill ----------------
__global__ __launch_bounds__(256) void zero_kernel(uint4* __restrict__ p, int n16) {
  int i = blockIdx.x * 256 + threadIdx.x;
  int stride = gridDim.x * 256;
  for (; i < n16; i += stride) p[i] = make_uint4(0, 0, 0, 0);
}

// ---------------- cast fp32 -> bf16 ----------------
__global__ __launch_bounds__(256) void cast_bf16(const float* __restrict__ in,
                                                 ushort* __restrict__ outb, int n) {
  int i = (blockIdx.x * blockDim.x + threadIdx.x) * 4;
  if (i >= n) return;
  float4 v = *(const float4*)(in + i);
  ushort4 o = make_ushort4(f2bf(v.x), f2bf(v.y), f2bf(v.z), f2bf(v.w));
  *(ushort4*)(outb + i) = o;
}

// ---------------- transpose + cast: in[R][C] fp32 -> out[C][R] bf16 ----------------
__global__ __launch_bounds__(256) void transpose_cast(const float* __restrict__ in,
                                                      ushort* __restrict__ outb,
                                                      int R, int C) {
  __shared__ float tile[32][33];
  int tx = threadIdx.x & 31, ty = threadIdx.x >> 5;
  int bx = blockIdx.x * 32;
  int by = blockIdx.y * 32;
#pragma unroll
  for (int r = 0; r < 4; ++r)
    tile[ty + r * 8][tx] = in[(size_t)(by + ty + r * 8) * C + bx + tx];
  __syncthreads();
#pragma unroll
  for (int r = 0; r < 4; ++r)
    outb[(size_t)(bx + ty + r * 8) * R + by + tx] = f2bf(tile[tx][ty + r * 8]);
}

// ---------------- pool-weight transpose: [c][27] -> [tap][c], 3 tensors ----------------
__global__ __launch_bounds__(256) void wpool_transpose(const float* __restrict__ wq,
                                                       const float* __restrict__ wk,
                                                       const float* __restrict__ wv,
                                                       float* __restrict__ wT) {
  int i = blockIdx.x * blockDim.x + threadIdx.x;
  if (i >= 3 * 27 * 64) return;
  int s = i / (27 * 64), r = i % (27 * 64), tap = r / 64, c = r % 64;
  const float* src = (s == 0) ? wq : ((s == 1) ? wk : wv);
  wT[i] = src[c * 27 + tap];
}

// ---------------- bf16 MFMA GEMM ----------------
template<int EPI>
__global__ __launch_bounds__(256) void gemm_mfma(const ushort* __restrict__ A,
                                                 const ushort* __restrict__ Bt,
                                                 const float* __restrict__ bias,
                                                 float* __restrict__ outf,
                                                 ushort* __restrict__ outp,
                                                 int M, int N, int K) {
  __shared__ ushort As[128][40];
  __shared__ ushort Bs[128][40];
  const int tid = threadIdx.x;
  const int wave = tid >> 6, lane = tid & 63;
  const int quad = lane >> 4, l16 = lane & 15;
  const int row0 = blockIdx.y * 128;
  const int col0 = blockIdx.x * 128;
  const int wm = (wave & 1) * 64;
  const int wn = (wave >> 1) * 64;

  f32x4 acc[4][4];
#pragma unroll
  for (int i = 0; i < 4; ++i)
#pragma unroll
    for (int j = 0; j < 4; ++j) acc[i][j] = (f32x4){0.f, 0.f, 0.f, 0.f};

  const int ar = tid >> 2;
  const int ak = (tid & 3) * 8;

  for (int k0 = 0; k0 < K; k0 += 32) {
    uint4 a0 = *(const uint4*)(A + (size_t)(row0 + ar) * K + k0 + ak);
    uint4 a1 = *(const uint4*)(A + (size_t)(row0 + ar + 64) * K + k0 + ak);
    uint4 b0 = *(const uint4*)(Bt + (size_t)(col0 + ar) * K + k0 + ak);
    uint4 b1 = *(const uint4*)(Bt + (size_t)(col0 + ar + 64) * K + k0 + ak);
    __syncthreads();
    *(uint4*)&As[ar][ak] = a0;
    *(uint4*)&As[ar + 64][ak] = a1;
    *(uint4*)&Bs[ar][ak] = b0;
    *(uint4*)&Bs[ar + 64][ak] = b1;
    __syncthreads();
    bf16x8 af[4], bfr[4];
#pragma unroll
    for (int i = 0; i < 4; ++i)
      af[i] = *(const bf16x8*)&As[wm + i * 16 + l16][quad * 8];
#pragma unroll
    for (int j = 0; j < 4; ++j)
      bfr[j] = *(const bf16x8*)&Bs[wn + j * 16 + l16][quad * 8];
#pragma unroll
    for (int i = 0; i < 4; ++i)
#pragma unroll
      for (int j = 0; j < 4; ++j)
        acc[i][j] = __builtin_amdgcn_mfma_f32_16x16x32_bf16(af[i], bfr[j], acc[i][j], 0, 0, 0);
  }

#pragma unroll
  for (int i = 0; i < 4; ++i) {
#pragma unroll
    for (int j = 0; j < 4; ++j) {
      int col = col0 + wn + j * 16 + l16;
      float bv = bias[col];
#pragma unroll
      for (int r = 0; r < 4; ++r) {
        int row = row0 + wm + i * 16 + quad * 4 + r;
        float val = acc[i][j][r] + bv;
        if (EPI == 0) {
          outf[(size_t)row * N + col] = val;
        } else {
          int b = row / NQ, nn = row % NQ;
          int s = col / DIM, rr = col % DIM;
          int h = rr >> 6, cc = rr & 63;
          int t = nn / 196, r2 = nn % 196, y = r2 / 14, xx = r2 % 14;
          size_t pidx = (((size_t)s * BATCH * NH + b * NH + h) * PVOL
                         + (t + 1) * PPLANE + (y + 1) * 16 + (xx + 1)) * (size_t)HD + cc;
          outp[pidx] = f2bf(val);
        }
      }
    }
  }
}

// ---------------- padded depthwise pool + LayerNorm(64) -> bf16 ----------------
template<int SW, int VT>
__global__ __launch_bounds__(256) void pool_ln_pad(const ushort* __restrict__ in,
                                                   ushort* __restrict__ out,
                                                   const float* __restrict__ wT,
                                                   const float* __restrict__ g,
                                                   const float* __restrict__ bb,
                                                   int OH, int OW) {
  const int OL = 8 * OH * OW;
  const int wid = (blockIdx.x * blockDim.x + threadIdx.x) >> 6;
  const int lane = threadIdx.x & 63;
  const int total = BATCH * NH * OL;
  if (wid >= total) return;
  const int bh = wid / OL, opos = wid % OL;
  const int ot = opos / (OH * OW);
  const int r = opos % (OH * OW);
  const int oy = r / OW, ox = r % OW;
  const int c = lane;
  const ushort* base = in + ((size_t)bh * PVOL + ot * PPLANE + oy * SW * 16 + ox * SW) * HD + c;

  float v[27], wv[27];
#pragma unroll
  for (int dt = 0; dt < 3; ++dt)
#pragma unroll
    for (int dy = 0; dy < 3; ++dy)
#pragma unroll
      for (int dx = 0; dx < 3; ++dx) {
        int i = (dt * 3 + dy) * 3 + dx;
        v[i] = bf2f(base[(size_t)(dt * PPLANE + dy * 16 + dx) * HD]);
        wv[i] = wT[i * 64 + c];
      }
  float acc = 0.f;
#pragma unroll
  for (int i = 0; i < 27; ++i) acc += v[i] * wv[i];

  float s = acc;
#pragma unroll
  for (int off = 32; off; off >>= 1) s += __shfl_xor(s, off, 64);
  float mean = s * (1.f / 64.f);
  float d = acc - mean;
  float vs = d * d;
#pragma unroll
  for (int off = 32; off; off >>= 1) vs += __shfl_xor(vs, off, 64);
  float inv = rsqrtf(vs * (1.f / 64.f) + EPS);
  float res = d * inv * g[c] + bb[c];
  if (VT == 0) out[(size_t)wid * HD + c] = f2bf(res);
  else         out[((size_t)bh * HD + c) * OL + opos] = f2bf(res);
}

// ---------------- rel-pos bias precompute (bf16 q) ----------------
__global__ __launch_bounds__(256) void rel_kernel(const ushort* __restrict__ qp,
                                                  const float* __restrict__ Rh,
                                                  const float* __restrict__ Rw,
                                                  const float* __restrict__ Rt,
                                                  float* __restrict__ rel) {
  const int idx = blockIdx.x * blockDim.x + threadIdx.x;
  const int total = BATCH * NH * NQ * 22;
  if (idx >= total) return;
  const int j = idx % 22;
  const int q = idx / 22;
  const int n = q % NQ;
  const int t = n / (HH_ * WW_);
  const int r = n % (HH_ * WW_);
  const int y = r / WW_, x = r % WW_;
  const float* R;
  if (j < 7)       R = Rh + (size_t)(y - 2 * j + 12) * HD;
  else if (j < 14) R = Rw + (size_t)(x - 2 * (j - 7) + 12) * HD;
  else             R = Rt + (size_t)(t - (j - 14) + 7) * HD;
  const ushort* qrow = qp + (size_t)q * HD;
  float acc = 0.f;
#pragma unroll 2
  for (int c = 0; c < HD; c += 8) {
    uint4 qa = *(const uint4*)(qrow + c);
    float4 r0 = *(const float4*)(R + c);
    float4 r1 = *(const float4*)(R + c + 4);
    acc += bfl(qa.x) * r0.x + bfh(qa.x) * r0.y + bfl(qa.y) * r0.z + bfh(qa.y) * r0.w;
    acc += bfl(qa.z) * r1.x + bfh(qa.z) * r1.y + bfl(qa.w) * r1.z + bfh(qa.w) * r1.w;
  }
  rel[(size_t)q * 24 + j] = acc;
}

// ---------------- MFMA attention: 32 queries/block, register softmax ----------------
// waves split K-tiles (tg = c*4+w); row stats combined cross-wave via tiny LDS.
__global__ __launch_bounds__(256) void attn_mfma(const ushort* __restrict__ qp,
                                                 const ushort* __restrict__ kp,
                                                 const ushort* __restrict__ vT,
                                                 const float* __restrict__ rel,
                                                 ushort* __restrict__ outb) {
  __shared__ ushort sQ[32][72];
  __shared__ ushort sK[64][72];      // K chunks, reused for V^T chunks
  __shared__ ushort sP[32][424];     // P bf16, pitch 424 (212 dw ≡ 20 mod 32: ≤2-way)
  __shared__ float sRel[32][24];
  __shared__ float sMax[32][4];
  __shared__ float sSum[32][4];
  const int qb = blockIdx.x;        // 0..48
  const int bh = blockIdx.y;        // 0..95
  const int b = bh / NH, h = bh % NH;
  const int tid = threadIdx.x;
  const int w = tid >> 6, lane = tid & 63;
  const int quad = lane >> 4, l16 = lane & 15;
  const int q0 = qb * 32;

  // stage Q (32x64 bf16 = 256 uint4) + rel + zero P pad cols 400..415
  {
    int row = tid >> 3, off = (tid & 7) * 8;
    *(uint4*)&sQ[row][off] = *(const uint4*)(qp + ((size_t)bh * NQ + q0 + row) * HD + off);
  }
  for (int e = tid; e < 32 * 22; e += 256) {
    int row = e / 22, j = e % 22;
    sRel[row][j] = rel[((size_t)bh * NQ + q0 + row) * 24 + j];
  }
  if (tid < 64) {
    int row = tid >> 1, seg = tid & 1;
    *(uint4*)&sP[row][400 + seg * 8] = make_uint4(0, 0, 0, 0);
  }
  __syncthreads();

  bf16x8 af[2][2];
#pragma unroll
  for (int t = 0; t < 2; ++t) {
    af[t][0] = *(const bf16x8*)&sQ[t * 16 + l16][quad * 8];
    af[t][1] = *(const bf16x8*)&sQ[t * 16 + l16][32 + quad * 8];
  }

  f32x4 acc[7][2];
#pragma unroll
  for (int c = 0; c < 7; ++c)
#pragma unroll
    for (int t = 0; t < 2; ++t) acc[c][t] = (f32x4){0.f, 0.f, 0.f, 0.f};

  const ushort* kbase = kp + (size_t)bh * LK * HD;

  // ---- QK^T ----
  for (int c = 0; c < 7; ++c) {
    __syncthreads();
#pragma unroll
    for (int i = 0; i < 2; ++i) {
      int e = tid + i * 256;
      int row = e >> 3, off = (e & 7) * 8;
      int kr = c * 64 + row;
      uint4 val = make_uint4(0, 0, 0, 0);
      if (kr < LK) val = *(const uint4*)(kbase + (size_t)kr * HD + off);
      *(uint4*)&sK[row][off] = val;
    }
    __syncthreads();
    int tg = c * 4 + w;
    if (tg < 25) {
      bf16x8 b0 = *(const bf16x8*)&sK[w * 16 + l16][quad * 8];
      bf16x8 b1 = *(const bf16x8*)&sK[w * 16 + l16][32 + quad * 8];
#pragma unroll
      for (int t = 0; t < 2; ++t) {
        acc[c][t] = __builtin_amdgcn_mfma_f32_16x16x32_bf16(af[t][0], b0, acc[c][t], 0, 0, 0);
        acc[c][t] = __builtin_amdgcn_mfma_f32_16x16x32_bf16(af[t][1], b1, acc[c][t], 0, 0, 0);
      }
    }
  }

  // ---- logits in registers: scale + rel bias (C-layout: col=l16->kg, row=quad*4+r) ----
#pragma unroll
  for (int c = 0; c < 7; ++c) {
    int tg = c * 4 + w;
    int kg = tg * 16 + l16;
    if (tg < 25 && kg < LK) {
      int kt = kg / 49, kr2 = kg % 49, ky = kr2 / 7, kx = kr2 % 7;
#pragma unroll
      for (int t = 0; t < 2; ++t)
#pragma unroll
        for (int r = 0; r < 4; ++r) {
          int q = t * 16 + quad * 4 + r;
          acc[c][t][r] = acc[c][t][r] * SCALE + sRel[q][ky] + sRel[q][7 + kx] + sRel[q][14 + kt];
        }
    } else {
#pragma unroll
      for (int t = 0; t < 2; ++t)
#pragma unroll
        for (int r = 0; r < 4; ++r) acc[c][t][r] = -1e30f;
    }
  }

  // ---- partial row max (over own k-cols), quad-local shuffle, cross-wave combine ----
  float pmax[2][4];
#pragma unroll
  for (int t = 0; t < 2; ++t)
#pragma unroll
    for (int r = 0; r < 4; ++r) {
      float m = acc[0][t][r];
#pragma unroll
      for (int c = 1; c < 7; ++c) m = fmaxf(m, acc[c][t][r]);
#pragma unroll
      for (int off = 1; off < 16; off <<= 1) m = fmaxf(m, __shfl_xor(m, off, 64));
      pmax[t][r] = m;
    }
  if (l16 == 0) {
#pragma unroll
    for (int t = 0; t < 2; ++t)
#pragma unroll
      for (int r = 0; r < 4; ++r) sMax[t * 16 + quad * 4 + r][w] = pmax[t][r];
  }
  __syncthreads();

  float M[2][4];
#pragma unroll
  for (int t = 0; t < 2; ++t)
#pragma unroll
    for (int r = 0; r < 4; ++r) {
      float4 mm = *(float4*)&sMax[t * 16 + quad * 4 + r][0];
      M[t][r] = fmaxf(fmaxf(mm.x, mm.y), fmaxf(mm.z, mm.w));
    }

  // ---- exp in registers, partial sums, P write (bf16, A-layout) ----
  float psum[2][4];
#pragma unroll
  for (int t = 0; t < 2; ++t)
#pragma unroll
    for (int r = 0; r < 4; ++r) psum[t][r] = 0.f;
#pragma unroll
  for (int c = 0; c < 7; ++c) {
#pragma unroll
    for (int t = 0; t < 2; ++t)
#pragma unroll
      for (int r = 0; r < 4; ++r) {
        float e = __expf(acc[c][t][r] - M[t][r]);
        acc[c][t][r] = e;
        psum[t][r] += e;
      }
  }
#pragma unroll
  for (int t = 0; t < 2; ++t)
#pragma unroll
    for (int r = 0; r < 4; ++r) {
      float s = psum[t][r];
#pragma unroll
      for (int off = 1; off < 16; off <<= 1) s += __shfl_xor(s, off, 64);
      psum[t][r] = s;
    }
  if (l16 == 0) {
#pragma unroll
    for (int t = 0; t < 2; ++t)
#pragma unroll
      for (int r = 0; r < 4; ++r) sSum[t * 16 + quad * 4 + r][w] = psum[t][r];
  }
#pragma unroll
  for (int c = 0; c < 7; ++c) {
    int tg = c * 4 + w;
    if (tg < 25) {
      int kg = tg * 16 + l16;
#pragma unroll
      for (int t = 0; t < 2; ++t)
#pragma unroll
        for (int r = 0; r < 4; ++r)
          sP[t * 16 + quad * 4 + r][kg] = f2bf(acc[c][t][r]);
    }
  }
  __syncthreads();

  float rinv[2][4];
#pragma unroll
  for (int t = 0; t < 2; ++t)
#pragma unroll
    for (int r = 0; r < 4; ++r) {
      float4 ss = *(float4*)&sSum[t * 16 + quad * 4 + r][0];
      rinv[t][r] = 1.f / (ss.x + ss.y + ss.z + ss.w);
    }

  // ---- PV: O[32][64] = P x V^T ----
  f32x4 oacc[2];
  oacc[0] = (f32x4){0.f, 0.f, 0.f, 0.f};
  oacc[1] = (f32x4){0.f, 0.f, 0.f, 0.f};
  const ushort* vbase = vT + (size_t)bh * HD * LK;
  for (int c = 0; c < 7; ++c) {
    __syncthreads();
#pragma unroll
    for (int i = 0; i < 2; ++i) {
      int e = tid + i * 256;
      int row = e >> 3, off = (e & 7) * 8;   // row=channel, off=kpos offset
      int kr = c * 64 + off;
      uint4 val = make_uint4(0, 0, 0, 0);
      if (kr + 7 < LK) val = *(const uint4*)(vbase + (size_t)row * LK + kr);
      *(uint4*)&sK[row][off] = val;
    }
    __syncthreads();
    int ksteps = (c == 6) ? 1 : 2;
    for (int s = 0; s < ksteps; ++s) {
      int kb = c * 64 + s * 32;
      bf16x8 vb = *(const bf16x8*)&sK[w * 16 + l16][s * 32 + quad * 8];
#pragma unroll
      for (int t = 0; t < 2; ++t) {
        bf16x8 pa = *(const bf16x8*)&sP[t * 16 + l16][kb + quad * 8];
        oacc[t] = __builtin_amdgcn_mfma_f32_16x16x32_bf16(pa, vb, oacc[t], 0, 0, 0);
      }
    }
  }

#pragma unroll
  for (int t = 0; t < 2; ++t)
#pragma unroll
    for (int r = 0; r < 4; ++r) {
      int q = q0 + t * 16 + quad * 4 + r;
      outb[((size_t)b * NQ + q) * DIM + h * HD + w * 16 + l16] = f2bf(oacc[t][r] * rinv[t][r]);
    }
}

// ---------------- launch ----------------
extern "C" void kernel_launch(void* const* d_in, const int* in_sizes, int n_in,
                              void* d_out, int out_size, void* d_ws, size_t ws_size,
                              hipStream_t stream) {
  const float* x        = (const float*)d_in[0];
  const float* w_qkv    = (const float*)d_in[1];
  const float* b_qkv    = (const float*)d_in[2];
  const float* pool_q_w = (const float*)d_in[3];
  const float* pool_k_w = (const float*)d_in[4];
  const float* pool_v_w = (const float*)d_in[5];
  const float* norm_q_g = (const float*)d_in[6];
  const float* norm_q_b = (const float*)d_in[7];
  const float* norm_k_g = (const float*)d_in[8];
  const float* norm_k_b = (const float*)d_in[9];
  const float* norm_v_g = (const float*)d_in[10];
  const float* norm_v_b = (const float*)d_in[11];
  const float* rel_h    = (const float*)d_in[12];
  const float* rel_w    = (const float*)d_in[13];
  const float* rel_t    = (const float*)d_in[14];
  const float* w_proj   = (const float*)d_in[15];
  const float* b_proj   = (const float*)d_in[16];
  float* out = (float*)d_out;

  const size_t NT  = (size_t)BATCH * NH * NQ * HD;
  const size_t LKT = (size_t)BATCH * NH * LK * HD;
  const size_t RELN = (size_t)BATCH * NH * NQ * 24;

  ushort* padQ = (ushort*)d_ws;                 // 3*PS bf16
  ushort* qpb  = padQ + 3 * PS;                 // NT bf16
  ushort* kpb  = qpb + NT;                      // LKT bf16
  ushort* vTb  = kpb + LKT;                     // LKT bf16 ([bh][c][kpos])
  float*  relb = (float*)(vTb + LKT);           // RELN fp32
  ushort* wqkvT = (ushort*)(relb + RELN);
  ushort* wprojT = wqkvT + (size_t)DIM * 3 * DIM;
  float*  wpoolT = (float*)(wprojT + (size_t)DIM * DIM);
  ushort* xb = qpb;                   // overlay: dead before pool writes qpb
  ushort* attn_outb = padQ;           // overlay: padQ dead after pools

  const int M = BATCH * NQ;  // 12544

  zero_kernel<<<2048, 256, 0, stream>>>((uint4*)padQ, (int)(3 * PS * 2 / 16));
  {
    int n = M * DIM;
    cast_bf16<<<(n / 4 + 255) / 256, 256, 0, stream>>>(x, xb, n);
    transpose_cast<<<dim3(3 * DIM / 32, DIM / 32), 256, 0, stream>>>(w_qkv, wqkvT, DIM, 3 * DIM);
    transpose_cast<<<dim3(DIM / 32, DIM / 32), 256, 0, stream>>>(w_proj, wprojT, DIM, DIM);
    wpool_transpose<<<(3 * 27 * 64 + 255) / 256, 256, 0, stream>>>(
        pool_q_w, pool_k_w, pool_v_w, wpoolT);
  }

  gemm_mfma<1><<<dim3(3 * DIM / 128, M / 128), 256, 0, stream>>>(
      xb, wqkvT, b_qkv, nullptr, padQ, M, 3 * DIM, DIM);

  {
    int wq = BATCH * NH * NQ;
    pool_ln_pad<1, 0><<<(wq + 3) / 4, 256, 0, stream>>>(
        padQ, qpb, wpoolT, norm_q_g, norm_q_b, 14, 14);
    int wk = BATCH * NH * LK;
    pool_ln_pad<2, 0><<<(wk + 3) / 4, 256, 0, stream>>>(
        padQ + PS, kpb, wpoolT + 27 * 64, norm_k_g, norm_k_b, 7, 7);
    pool_ln_pad<2, 1><<<(wk + 3) / 4, 256, 0, stream>>>(
        padQ + 2 * PS, vTb, wpoolT + 2 * 27 * 64, norm_v_g, norm_v_b, 7, 7);
  }

  {
    int total = BATCH * NH * NQ * 22;
    rel_kernel<<<(total + 255) / 256, 256, 0, stream>>>(qpb, rel_h, rel_w, rel_t, relb);
  }

  attn_mfma<<<dim3(NQ / 32, BATCH * NH), 256, 0, stream>>>(qpb, kpb, vTb, relb, attn_outb);

  gemm_mfma<0><<<dim3(DIM / 128, M / 128), 256, 0, stream>>>(
      attn_outb, wprojT, b_proj, out, nullptr, M, DIM, DIM);
}

// Round 8
// 586.335 us; speedup vs baseline: 19.9980x; 1.0483x over previous
//
#include <hip/hip_runtime.h>
#include <hip/hip_bf16.h>

#define BATCH 8
#define NH 12
#define DIM 768
#define HD 64
#define NQ 1568       // 8*14*14
#define TT 8
#define HH_ 14
#define WW_ 14
#define LK 392        // 8*7*7
#define LKP 416       // padded V^T row pitch (13*32), zero tail
#define SCALE 0.125f
#define EPS 1e-5f

// padded pool-input layout: [s][bh][pt 0..9][py 0..15][px 0..15][c]
#define PT 10
#define PPLANE 256            // 16*16
#define PVOL 2560             // PT*PPLANE
#define PS ((size_t)BATCH * NH * PVOL * HD)   // elems per s-third

typedef __bf16 bf16x8 __attribute__((ext_vector_type(8)));
typedef float f32x4 __attribute__((ext_vector_type(4)));

__device__ inline ushort f2bf(float f) {
  uint u = __float_as_uint(f);
  u += 0x7FFF + ((u >> 16) & 1);   // RNE
  return (ushort)(u >> 16);
}
__device__ inline float bf2f(ushort v) { return __uint_as_float((uint)v << 16); }
__device__ inline float bfl(uint u) { return __uint_as_float(u << 16); }
__device__ inline float bfh(uint u) { return __uint_as_float(u & 0xffff0000u); }

// ---------------- zero fill ----------------
__global__ __launch_bounds__(256) void zero_kernel(uint4* __restrict__ p, int n16) {
  int i = blockIdx.x * 256 + threadIdx.x;
  int stride = gridDim.x * 256;
  for (; i < n16; i += stride) p[i] = make_uint4(0, 0, 0, 0);
}

// ---------------- cast fp32 -> bf16 ----------------
__global__ __launch_bounds__(256) void cast_bf16(const float* __restrict__ in,
                                                 ushort* __restrict__ outb, int n) {
  int i = (blockIdx.x * blockDim.x + threadIdx.x) * 4;
  if (i >= n) return;
  float4 v = *(const float4*)(in + i);
  ushort4 o = make_ushort4(f2bf(v.x), f2bf(v.y), f2bf(v.z), f2bf(v.w));
  *(ushort4*)(outb + i) = o;
}

// ---------------- transpose + cast: in[R][C] fp32 -> out[C][R] bf16 ----------------
__global__ __launch_bounds__(256) void transpose_cast(const float* __restrict__ in,
                                                      ushort* __restrict__ outb,
                                                      int R, int C) {
  __shared__ float tile[32][33];
  int tx = threadIdx.x & 31, ty = threadIdx.x >> 5;
  int bx = blockIdx.x * 32;
  int by = blockIdx.y * 32;
#pragma unroll
  for (int r = 0; r < 4; ++r)
    tile[ty + r * 8][tx] = in[(size_t)(by + ty + r * 8) * C + bx + tx];
  __syncthreads();
#pragma unroll
  for (int r = 0; r < 4; ++r)
    outb[(size_t)(bx + ty + r * 8) * R + by + tx] = f2bf(tile[tx][ty + r * 8]);
}

// ---------------- pool-weight transpose: [c][27] -> [tap][c], 3 tensors ----------------
__global__ __launch_bounds__(256) void wpool_transpose(const float* __restrict__ wq,
                                                       const float* __restrict__ wk,
                                                       const float* __restrict__ wv,
                                                       float* __restrict__ wT) {
  int i = blockIdx.x * blockDim.x + threadIdx.x;
  if (i >= 3 * 27 * 64) return;
  int s = i / (27 * 64), r = i % (27 * 64), tap = r / 64, c = r % 64;
  const float* src = (s == 0) ? wq : ((s == 1) ? wk : wv);
  wT[i] = src[c * 27 + tap];
}

// ---------------- bf16 MFMA GEMM ----------------
template<int EPI>
__global__ __launch_bounds__(256) void gemm_mfma(const ushort* __restrict__ A,
                                                 const ushort* __restrict__ Bt,
                                                 const float* __restrict__ bias,
                                                 float* __restrict__ outf,
                                                 ushort* __restrict__ outp,
                                                 int M, int N, int K) {
  __shared__ ushort As[128][40];
  __shared__ ushort Bs[128][40];
  const int tid = threadIdx.x;
  const int wave = tid >> 6, lane = tid & 63;
  const int quad = lane >> 4, l16 = lane & 15;
  const int row0 = blockIdx.y * 128;
  const int col0 = blockIdx.x * 128;
  const int wm = (wave & 1) * 64;
  const int wn = (wave >> 1) * 64;

  f32x4 acc[4][4];
#pragma unroll
  for (int i = 0; i < 4; ++i)
#pragma unroll
    for (int j = 0; j < 4; ++j) acc[i][j] = (f32x4){0.f, 0.f, 0.f, 0.f};

  const int ar = tid >> 2;
  const int ak = (tid & 3) * 8;

  for (int k0 = 0; k0 < K; k0 += 32) {
    uint4 a0 = *(const uint4*)(A + (size_t)(row0 + ar) * K + k0 + ak);
    uint4 a1 = *(const uint4*)(A + (size_t)(row0 + ar + 64) * K + k0 + ak);
    uint4 b0 = *(const uint4*)(Bt + (size_t)(col0 + ar) * K + k0 + ak);
    uint4 b1 = *(const uint4*)(Bt + (size_t)(col0 + ar + 64) * K + k0 + ak);
    __syncthreads();
    *(uint4*)&As[ar][ak] = a0;
    *(uint4*)&As[ar + 64][ak] = a1;
    *(uint4*)&Bs[ar][ak] = b0;
    *(uint4*)&Bs[ar + 64][ak] = b1;
    __syncthreads();
    bf16x8 af[4], bfr[4];
#pragma unroll
    for (int i = 0; i < 4; ++i)
      af[i] = *(const bf16x8*)&As[wm + i * 16 + l16][quad * 8];
#pragma unroll
    for (int j = 0; j < 4; ++j)
      bfr[j] = *(const bf16x8*)&Bs[wn + j * 16 + l16][quad * 8];
#pragma unroll
    for (int i = 0; i < 4; ++i)
#pragma unroll
      for (int j = 0; j < 4; ++j)
        acc[i][j] = __builtin_amdgcn_mfma_f32_16x16x32_bf16(af[i], bfr[j], acc[i][j], 0, 0, 0);
  }

#pragma unroll
  for (int i = 0; i < 4; ++i) {
#pragma unroll
    for (int j = 0; j < 4; ++j) {
      int col = col0 + wn + j * 16 + l16;
      float bv = bias[col];
#pragma unroll
      for (int r = 0; r < 4; ++r) {
        int row = row0 + wm + i * 16 + quad * 4 + r;
        float val = acc[i][j][r] + bv;
        if (EPI == 0) {
          outf[(size_t)row * N + col] = val;
        } else {
          int b = row / NQ, nn = row % NQ;
          int s = col / DIM, rr = col % DIM;
          int h = rr >> 6, cc = rr & 63;
          int t = nn / 196, r2 = nn % 196, y = r2 / 14, xx = r2 % 14;
          size_t pidx = (((size_t)s * BATCH * NH + b * NH + h) * PVOL
                         + (t + 1) * PPLANE + (y + 1) * 16 + (xx + 1)) * (size_t)HD + cc;
          outp[pidx] = f2bf(val);
        }
      }
    }
  }
}

// ---------------- padded depthwise pool + LayerNorm(64) -> bf16 ----------------
template<int SW, int VT>
__global__ __launch_bounds__(256) void pool_ln_pad(const ushort* __restrict__ in,
                                                   ushort* __restrict__ out,
                                                   const float* __restrict__ wT,
                                                   const float* __restrict__ g,
                                                   const float* __restrict__ bb,
                                                   int OH, int OW) {
  const int OL = 8 * OH * OW;
  const int wid = (blockIdx.x * blockDim.x + threadIdx.x) >> 6;
  const int lane = threadIdx.x & 63;
  const int total = BATCH * NH * OL;
  if (wid >= total) return;
  const int bh = wid / OL, opos = wid % OL;
  const int ot = opos / (OH * OW);
  const int r = opos % (OH * OW);
  const int oy = r / OW, ox = r % OW;
  const int c = lane;
  const ushort* base = in + ((size_t)bh * PVOL + ot * PPLANE + oy * SW * 16 + ox * SW) * HD + c;

  float v[27], wv[27];
#pragma unroll
  for (int dt = 0; dt < 3; ++dt)
#pragma unroll
    for (int dy = 0; dy < 3; ++dy)
#pragma unroll
      for (int dx = 0; dx < 3; ++dx) {
        int i = (dt * 3 + dy) * 3 + dx;
        v[i] = bf2f(base[(size_t)(dt * PPLANE + dy * 16 + dx) * HD]);
        wv[i] = wT[i * 64 + c];
      }
  float acc = 0.f;
#pragma unroll
  for (int i = 0; i < 27; ++i) acc += v[i] * wv[i];

  float s = acc;
#pragma unroll
  for (int off = 32; off; off >>= 1) s += __shfl_xor(s, off, 64);
  float mean = s * (1.f / 64.f);
  float d = acc - mean;
  float vs = d * d;
#pragma unroll
  for (int off = 32; off; off >>= 1) vs += __shfl_xor(vs, off, 64);
  float inv = rsqrtf(vs * (1.f / 64.f) + EPS);
  float res = d * inv * g[c] + bb[c];
  if (VT == 0) out[(size_t)wid * HD + c] = f2bf(res);
  else         out[((size_t)bh * HD + c) * LKP + opos] = f2bf(res);
}

// ---------------- rel-pos bias precompute (bf16 q) ----------------
__global__ __launch_bounds__(256) void rel_kernel(const ushort* __restrict__ qp,
                                                  const float* __restrict__ Rh,
                                                  const float* __restrict__ Rw,
                                                  const float* __restrict__ Rt,
                                                  float* __restrict__ rel) {
  const int idx = blockIdx.x * blockDim.x + threadIdx.x;
  const int total = BATCH * NH * NQ * 22;
  if (idx >= total) return;
  const int j = idx % 22;
  const int q = idx / 22;
  const int n = q % NQ;
  const int t = n / (HH_ * WW_);
  const int r = n % (HH_ * WW_);
  const int y = r / WW_, x = r % WW_;
  const float* R;
  if (j < 7)       R = Rh + (size_t)(y - 2 * j + 12) * HD;
  else if (j < 14) R = Rw + (size_t)(x - 2 * (j - 7) + 12) * HD;
  else             R = Rt + (size_t)(t - (j - 14) + 7) * HD;
  const ushort* qrow = qp + (size_t)q * HD;
  float acc = 0.f;
#pragma unroll 2
  for (int c = 0; c < HD; c += 8) {
    uint4 qa = *(const uint4*)(qrow + c);
    float4 r0 = *(const float4*)(R + c);
    float4 r1 = *(const float4*)(R + c + 4);
    acc += bfl(qa.x) * r0.x + bfh(qa.x) * r0.y + bfl(qa.y) * r0.z + bfh(qa.y) * r0.w;
    acc += bfl(qa.z) * r1.x + bfh(qa.z) * r1.y + bfl(qa.w) * r1.z + bfh(qa.w) * r1.w;
  }
  rel[(size_t)q * 24 + j] = acc;
}

// ---------------- MFMA attention: 32 queries/block, fragments direct from global ----
// No K/V LDS staging: B-fragments are 16B/lane contiguous global loads (L2-resident).
// LDS only holds P (bf16), rel, and stat-exchange arrays. 3 barriers total.
__global__ __launch_bounds__(256) void attn_mfma(const ushort* __restrict__ qp,
                                                 const ushort* __restrict__ kp,
                                                 const ushort* __restrict__ vT,
                                                 const float* __restrict__ rel,
                                                 ushort* __restrict__ outb) {
  __shared__ ushort sP[32][424];     // pitch 424: P-read (b128) spreads all banks
  __shared__ float sRel[32][24];
  __shared__ float sMax[32][4];
  __shared__ float sSum[32][4];
  const int qb = blockIdx.x;        // 0..48
  const int bh = blockIdx.y;        // 0..95
  const int b = bh / NH, h = bh % NH;
  const int tid = threadIdx.x;
  const int w = tid >> 6, lane = tid & 63;
  const int quad = lane >> 4, l16 = lane & 15;
  const int q0 = qb * 32;

  // stage rel + zero P pad cols 400..415
  for (int e = tid; e < 32 * 22; e += 256) {
    int row = e / 22, j = e % 22;
    sRel[row][j] = rel[((size_t)bh * NQ + q0 + row) * 24 + j];
  }
  if (tid < 64) {
    int row = tid >> 1, seg = tid & 1;
    *(uint4*)&sP[row][400 + seg * 8] = make_uint4(0, 0, 0, 0);
  }

  // Q A-fragments direct from global (same for all waves; 4x redundant, tiny)
  const ushort* qbase = qp + ((size_t)bh * NQ + q0) * HD;
  bf16x8 af[2][2];
#pragma unroll
  for (int t = 0; t < 2; ++t) {
    af[t][0] = *(const bf16x8*)(qbase + (size_t)(t * 16 + l16) * HD + quad * 8);
    af[t][1] = *(const bf16x8*)(qbase + (size_t)(t * 16 + l16) * HD + 32 + quad * 8);
  }

  f32x4 acc[7][2];
#pragma unroll
  for (int c = 0; c < 7; ++c)
#pragma unroll
    for (int t = 0; t < 2; ++t) acc[c][t] = (f32x4){0.f, 0.f, 0.f, 0.f};

  // ---- QK^T: wave w owns tiles tg = c*4+w; K B-fragments direct from global ----
  const ushort* kbase = kp + (size_t)bh * LK * HD;
#pragma unroll
  for (int c = 0; c < 7; ++c) {
    int tg = c * 4 + w;
    if (tg < 25) {
      int kg = tg * 16 + l16;
      int kgc = kg < LK ? kg : (LK - 1);   // clamp; masked below
      const ushort* krow = kbase + (size_t)kgc * HD;
      bf16x8 b0 = *(const bf16x8*)(krow + quad * 8);
      bf16x8 b1 = *(const bf16x8*)(krow + 32 + quad * 8);
#pragma unroll
      for (int t = 0; t < 2; ++t) {
        acc[c][t] = __builtin_amdgcn_mfma_f32_16x16x32_bf16(af[t][0], b0, acc[c][t], 0, 0, 0);
        acc[c][t] = __builtin_amdgcn_mfma_f32_16x16x32_bf16(af[t][1], b1, acc[c][t], 0, 0, 0);
      }
    }
  }
  __syncthreads();   // barrier 1: sRel (and sP pad) visible

  // ---- logits: scale + rel bias (C-layout: col=l16->kg, row=quad*4+r) ----
#pragma unroll
  for (int c = 0; c < 7; ++c) {
    int tg = c * 4 + w;
    int kg = tg * 16 + l16;
    if (tg < 25 && kg < LK) {
      int kt = kg / 49, kr2 = kg % 49, ky = kr2 / 7, kx = kr2 % 7;
#pragma unroll
      for (int t = 0; t < 2; ++t)
#pragma unroll
        for (int r = 0; r < 4; ++r) {
          int q = t * 16 + quad * 4 + r;
          acc[c][t][r] = acc[c][t][r] * SCALE + sRel[q][ky] + sRel[q][7 + kx] + sRel[q][14 + kt];
        }
    } else {
#pragma unroll
      for (int t = 0; t < 2; ++t)
#pragma unroll
        for (int r = 0; r < 4; ++r) acc[c][t][r] = -1e30f;
    }
  }

  // ---- row max: reduce over l16, exchange across waves ----
  float pmax[2][4];
#pragma unroll
  for (int t = 0; t < 2; ++t)
#pragma unroll
    for (int r = 0; r < 4; ++r) {
      float m = acc[0][t][r];
#pragma unroll
      for (int c = 1; c < 7; ++c) m = fmaxf(m, acc[c][t][r]);
#pragma unroll
      for (int off = 1; off < 16; off <<= 1) m = fmaxf(m, __shfl_xor(m, off, 64));
      pmax[t][r] = m;
    }
  if (l16 == 0) {
#pragma unroll
    for (int t = 0; t < 2; ++t)
#pragma unroll
      for (int r = 0; r < 4; ++r) sMax[t * 16 + quad * 4 + r][w] = pmax[t][r];
  }
  __syncthreads();   // barrier 2

  float M[2][4];
#pragma unroll
  for (int t = 0; t < 2; ++t)
#pragma unroll
    for (int r = 0; r < 4; ++r) {
      float4 mm = *(float4*)&sMax[t * 16 + quad * 4 + r][0];
      M[t][r] = fmaxf(fmaxf(mm.x, mm.y), fmaxf(mm.z, mm.w));
    }

  // ---- exp, partial sums, P write ----
  float psum[2][4];
#pragma unroll
  for (int t = 0; t < 2; ++t)
#pragma unroll
    for (int r = 0; r < 4; ++r) psum[t][r] = 0.f;
#pragma unroll
  for (int c = 0; c < 7; ++c) {
#pragma unroll
    for (int t = 0; t < 2; ++t)
#pragma unroll
      for (int r = 0; r < 4; ++r) {
        float e = __expf(acc[c][t][r] - M[t][r]);
        acc[c][t][r] = e;
        psum[t][r] += e;
      }
  }
#pragma unroll
  for (int t = 0; t < 2; ++t)
#pragma unroll
    for (int r = 0; r < 4; ++r) {
      float s = psum[t][r];
#pragma unroll
      for (int off = 1; off < 16; off <<= 1) s += __shfl_xor(s, off, 64);
      psum[t][r] = s;
    }
  if (l16 == 0) {
#pragma unroll
    for (int t = 0; t < 2; ++t)
#pragma unroll
      for (int r = 0; r < 4; ++r) sSum[t * 16 + quad * 4 + r][w] = psum[t][r];
  }
#pragma unroll
  for (int c = 0; c < 7; ++c) {
    int tg = c * 4 + w;
    if (tg < 25) {
      int kg = tg * 16 + l16;
#pragma unroll
      for (int t = 0; t < 2; ++t)
#pragma unroll
        for (int r = 0; r < 4; ++r)
          sP[t * 16 + quad * 4 + r][kg] = f2bf(acc[c][t][r]);
    }
  }
  __syncthreads();   // barrier 3

  float rinv[2][4];
#pragma unroll
  for (int t = 0; t < 2; ++t)
#pragma unroll
    for (int r = 0; r < 4; ++r) {
      float4 ss = *(float4*)&sSum[t * 16 + quad * 4 + r][0];
      rinv[t][r] = 1.f / (ss.x + ss.y + ss.z + ss.w);
    }

  // ---- PV: V^T B-fragments direct from global (padded pitch LKP, zero tail) ----
  f32x4 oacc[2];
  oacc[0] = (f32x4){0.f, 0.f, 0.f, 0.f};
  oacc[1] = (f32x4){0.f, 0.f, 0.f, 0.f};
  const ushort* vrow = vT + ((size_t)bh * HD + w * 16 + l16) * LKP;
#pragma unroll
  for (int s = 0; s < 13; ++s) {
    int kb = s * 32;
    bf16x8 vb = *(const bf16x8*)(vrow + kb + quad * 8);
#pragma unroll
    for (int t = 0; t < 2; ++t) {
      bf16x8 pa = *(const bf16x8*)&sP[t * 16 + l16][kb + quad * 8];
      oacc[t] = __builtin_amdgcn_mfma_f32_16x16x32_bf16(pa, vb, oacc[t], 0, 0, 0);
    }
  }

#pragma unroll
  for (int t = 0; t < 2; ++t)
#pragma unroll
    for (int r = 0; r < 4; ++r) {
      int q = q0 + t * 16 + quad * 4 + r;
      outb[((size_t)b * NQ + q) * DIM + h * HD + w * 16 + l16] = f2bf(oacc[t][r] * rinv[t][r]);
    }
}

// ---------------- launch ----------------
extern "C" void kernel_launch(void* const* d_in, const int* in_sizes, int n_in,
                              void* d_out, int out_size, void* d_ws, size_t ws_size,
                              hipStream_t stream) {
  const float* x        = (const float*)d_in[0];
  const float* w_qkv    = (const float*)d_in[1];
  const float* b_qkv    = (const float*)d_in[2];
  const float* pool_q_w = (const float*)d_in[3];
  const float* pool_k_w = (const float*)d_in[4];
  const float* pool_v_w = (const float*)d_in[5];
  const float* norm_q_g = (const float*)d_in[6];
  const float* norm_q_b = (const float*)d_in[7];
  const float* norm_k_g = (const float*)d_in[8];
  const float* norm_k_b = (const float*)d_in[9];
  const float* norm_v_g = (const float*)d_in[10];
  const float* norm_v_b = (const float*)d_in[11];
  const float* rel_h    = (const float*)d_in[12];
  const float* rel_w    = (const float*)d_in[13];
  const float* rel_t    = (const float*)d_in[14];
  const float* w_proj   = (const float*)d_in[15];
  const float* b_proj   = (const float*)d_in[16];
  float* out = (float*)d_out;

  const size_t NT  = (size_t)BATCH * NH * NQ * HD;
  const size_t LKT = (size_t)BATCH * NH * LK * HD;
  const size_t LKV = (size_t)BATCH * NH * HD * LKP;   // padded V^T
  const size_t RELN = (size_t)BATCH * NH * NQ * 24;

  ushort* padQ = (ushort*)d_ws;                 // 3*PS bf16
  ushort* qpb  = padQ + 3 * PS;                 // NT bf16
  ushort* kpb  = qpb + NT;                      // LKT bf16
  ushort* vTb  = kpb + LKT;                     // LKV bf16 ([bh][c][kpos], pitch LKP)
  float*  relb = (float*)(vTb + LKV);           // RELN fp32
  ushort* wqkvT = (ushort*)(relb + RELN);
  ushort* wprojT = wqkvT + (size_t)DIM * 3 * DIM;
  float*  wpoolT = (float*)(wprojT + (size_t)DIM * DIM);
  ushort* xb = qpb;                   // overlay: dead before pool writes qpb
  ushort* attn_outb = padQ;           // overlay: padQ dead after pools

  const int M = BATCH * NQ;  // 12544

  zero_kernel<<<2048, 256, 0, stream>>>((uint4*)padQ, (int)(3 * PS * 2 / 16));
  zero_kernel<<<256, 256, 0, stream>>>((uint4*)vTb, (int)(LKV * 2 / 16));
  {
    int n = M * DIM;
    cast_bf16<<<(n / 4 + 255) / 256, 256, 0, stream>>>(x, xb, n);
    transpose_cast<<<dim3(3 * DIM / 32, DIM / 32), 256, 0, stream>>>(w_qkv, wqkvT, DIM, 3 * DIM);
    transpose_cast<<<dim3(DIM / 32, DIM / 32), 256, 0, stream>>>(w_proj, wprojT, DIM, DIM);
    wpool_transpose<<<(3 * 27 * 64 + 255) / 256, 256, 0, stream>>>(
        pool_q_w, pool_k_w, pool_v_w, wpoolT);
  }

  gemm_mfma<1><<<dim3(3 * DIM / 128, M / 128), 256, 0, stream>>>(
      xb, wqkvT, b_qkv, nullptr, padQ, M, 3 * DIM, DIM);

  {
    int wq = BATCH * NH * NQ;
    pool_ln_pad<1, 0><<<(wq + 3) / 4, 256, 0, stream>>>(
        padQ, qpb, wpoolT, norm_q_g, norm_q_b, 14, 14);
    int wk = BATCH * NH * LK;
    pool_ln_pad<2, 0><<<(wk + 3) / 4, 256, 0, stream>>>(
        padQ + PS, kpb, wpoolT + 27 * 64, norm_k_g, norm_k_b, 7, 7);
    pool_ln_pad<2, 1><<<(wk + 3) / 4, 256, 0, stream>>>(
        padQ + 2 * PS, vTb, wpoolT + 2 * 27 * 64, norm_v_g, norm_v_b, 7, 7);
  }

  {
    int total = BATCH * NH * NQ * 22;
    rel_kernel<<<(total + 255) / 256, 256, 0, stream>>>(qpb, rel_h, rel_w, rel_t, relb);
  }

  attn_mfma<<<dim3(NQ / 32, BATCH * NH), 256, 0, stream>>>(qpb, kpb, vTb, relb, attn_outb);

  gemm_mfma<0><<<dim3(DIM / 128, M / 128), 256, 0, stream>>>(
      attn_outb, wprojT, b_proj, out, nullptr, M, DIM, DIM);
}